// Round 16
// baseline (185.674 us; speedup 1.0000x reference)
//
#include <hip/hip_runtime.h>
#include <hip/hip_bf16.h>
#include <cstdint>
#include <cstddef>

typedef __bf16 bf16;
typedef __bf16 bf16x2 __attribute__((ext_vector_type(2)));
typedef __bf16 bf16x4 __attribute__((ext_vector_type(4)));
typedef __bf16 bf16x8 __attribute__((ext_vector_type(8)));
typedef float f32x4 __attribute__((ext_vector_type(4)));
typedef float f32x16 __attribute__((ext_vector_type(16)));
typedef unsigned int u32x4 __attribute__((ext_vector_type(4)));

#define S_LEN 2048
#define DM 1024
#define NH 16
#define HD 64
#define NQKV (4096 * 1024)   // tokens * DM
#define NW (1024 * 1024)
// (1/sqrt(64)) * log2(e): fold softmax scale + exp2 conversion into Q
#define QK_SCALE 0.18033688011112042f

__device__ __forceinline__ void gload_lds16(const bf16* g, bf16* l) {
  __builtin_amdgcn_global_load_lds(
      (const __attribute__((address_space(1))) void*)g,
      (__attribute__((address_space(3))) void*)l, 16, 0, 0);
}

__device__ __forceinline__ unsigned packbf(float lo, float hi) {
  bf16x2 t;
  t[0] = (bf16)lo;
  t[1] = (bf16)hi;
  return __builtin_bit_cast(unsigned, t);
}

// v_permlane32_swap_b32: new_a[l>=32] = b_old[l-32]; new_b[l<32] = a_old[l+32]
__device__ __forceinline__ void pl32swap(unsigned& a, unsigned& b) {
#if __has_builtin(__builtin_amdgcn_permlane32_swap)
  auto r = __builtin_amdgcn_permlane32_swap((int)a, (int)b, false, false);
  a = (unsigned)r[0];
  b = (unsigned)r[1];
#else
  asm volatile("v_permlane32_swap_b32 %0, %1" : "+v"(a), "+v"(b));
#endif
}

// ---------------- fused fp32 -> bf16 convert for all 7 tensors ----------------
__global__ __launch_bounds__(256) void cvt_all(
    const float* __restrict__ q, const float* __restrict__ k, const float* __restrict__ v,
    const float* __restrict__ Wq, const float* __restrict__ Wk, const float* __restrict__ Wv,
    const float* __restrict__ Wo, bf16* __restrict__ out) {
  const size_t i = ((size_t)blockIdx.x * 256 + threadIdx.x) * 8;
  const float* src;
  size_t off;
  if (i < (size_t)NQKV) { src = q; off = i; }
  else if (i < 2ull * NQKV) { src = k; off = i - NQKV; }
  else if (i < 3ull * NQKV) { src = v; off = i - 2ull * NQKV; }
  else {
    const size_t j = i - 3ull * NQKV;
    if (j < (size_t)NW) { src = Wq; off = j; }
    else if (j < 2ull * NW) { src = Wk; off = j - NW; }
    else if (j < 3ull * NW) { src = Wv; off = j - 2ull * NW; }
    else { src = Wo; off = j - 3ull * NW; }
  }
  const float4 a = *(const float4*)(src + off);
  const float4 b = *(const float4*)(src + off + 4);
  bf16x8 o;
  o[0] = (bf16)a.x; o[1] = (bf16)a.y; o[2] = (bf16)a.z; o[3] = (bf16)a.w;
  o[4] = (bf16)b.x; o[5] = (bf16)b.y; o[6] = (bf16)b.z; o[7] = (bf16)b.w;
  *(bf16x8*)(out + i) = o;
}

// ---------------- GEMM: Y[m,n] = sum_k A[m,k] * W[n,k] + bias[n] ----------------
// (round-13 version restored: gload_lds A staging from pre-converted bf16)
// MODE 2: out fp32, row-major [M,N]   (final projection)
// MODE 3: fused QKV; seg = n0>>10: seg0 Q head-major*QK_SCALE, seg1 K head-major,
//         seg2 V per-head transposed [B,H,hd,S] via LDS-transposed epilogue.
template <int MODE>
__global__ __launch_bounds__(256, 3) void gemm_bt(
    const bf16* __restrict__ A, const bf16* __restrict__ W,
    const float* __restrict__ bias0, const float* __restrict__ bias1,
    const float* __restrict__ bias2, void* __restrict__ Out,
    int M, int N, int K, float scale) {
  __shared__ __align__(16) bf16 sm[2 * 128 * 64];
  bf16* Asl = sm;
  bf16* Bsl = sm + 128 * 64;
  const int tid = threadIdx.x;
  const int lane = tid & 63, w = tid >> 6;
  const int wr = w >> 1, wc = w & 1;
  const int r16 = lane & 15, grp = lane >> 4;

  // XCD swizzle: consecutive blocks within an XCD share A-panels
  int flat = blockIdx.y * gridDim.x + blockIdx.x;
  const int cpx = (gridDim.x * gridDim.y) >> 3;
  flat = (flat & 7) * cpx + (flat >> 3);
  const int m0 = (flat / gridDim.x) * 128;
  const int n0 = (flat % gridDim.x) * 128;

  const int seg = n0 >> 10;
  const bf16* Ab = (MODE == 3) ? A + (size_t)seg * NQKV : A;

  f32x4 acc[4][4] = {};

  const int nk = K >> 6;
  for (int t = 0; t < nk; ++t) {
    const int k0 = t << 6;
    __syncthreads();
#pragma unroll
    for (int j = 0; j < 4; ++j) {
      const int lin = j * 256 + tid;
      const int rr = lin >> 3;
      const int cc = (lin & 7) * 8;
      gload_lds16(&Ab[(size_t)(m0 + rr) * K + k0 + cc], &Asl[lin * 8]);
      gload_lds16(&W[(size_t)(n0 + rr) * K + k0 + cc], &Bsl[lin * 8]);
    }
    __syncthreads();
#pragma unroll
    for (int kk = 0; kk < 2; ++kk) {
      bf16x8 af[4], bfr[4];
#pragma unroll
      for (int m = 0; m < 4; ++m)
        af[m] = *(const bf16x8*)&Asl[(wr * 64 + m * 16 + r16) * 64 + kk * 32 + grp * 8];
#pragma unroll
      for (int n = 0; n < 4; ++n)
        bfr[n] = *(const bf16x8*)&Bsl[(wc * 64 + n * 16 + r16) * 64 + kk * 32 + grp * 8];
#pragma unroll
      for (int m = 0; m < 4; ++m)
#pragma unroll
        for (int n = 0; n < 4; ++n)
          acc[m][n] = __builtin_amdgcn_mfma_f32_16x16x32_bf16(af[m], bfr[n], acc[m][n], 0, 0, 0);
    }
  }

  const float* bp = (MODE == 3) ? (seg == 0 ? bias0 : (seg == 1 ? bias1 : bias2)) : bias0;
  const float sc = (MODE == 3) ? (seg == 0 ? scale : 1.0f) : scale;

  if (MODE == 3 && seg == 2) {
    // ---- V^T epilogue: transpose each wave's 64x64 quadrant via LDS ----
    __syncthreads();  // all Asl/Bsl readers done
    bf16* T = sm + w * (32 * 76);
    const int b = (m0 + wr * 64) >> 11;
    const int srow0 = (m0 + wr * 64) & 2047;
    bf16* base2 = (bf16*)Out + 2 * (size_t)NQKV;
#pragma unroll
    for (int p = 0; p < 2; ++p) {
#pragma unroll
      for (int nn = 0; nn < 2; ++nn) {
        const int n = 2 * p + nn;
#pragma unroll
        for (int mq = 0; mq < 4; ++mq)
#pragma unroll
          for (int r = 0; r < 4; ++r) {
            const int d_l = nn * 16 + r16;
            const int s_l = mq * 16 + grp * 4 + r;
            const int cs = (n0 + wc * 64 + n * 16 + r16) & 1023;
            T[d_l * 76 + s_l] = (bf16)(acc[mq][n][r] + bp[cs]);
          }
      }
      __syncthreads();
#pragma unroll
      for (int j = 0; j < 4; ++j) {
        const int d_l = j * 8 + (lane >> 3);
        const int scnk = lane & 7;
        const uint2 lo = *(const uint2*)&T[d_l * 76 + scnk * 8];
        const uint2 hi = *(const uint2*)&T[d_l * 76 + scnk * 8 + 4];
        const int cs = (n0 + wc * 64 + p * 32 + d_l) & 1023;
        const int hh = cs >> 6, dd = cs & 63;
        bf16* dst = base2 + ((size_t)(b * NH + hh) * HD + dd) * S_LEN + srow0 + scnk * 8;
        uint4 val; val.x = lo.x; val.y = lo.y; val.z = hi.x; val.w = hi.y;
        *(uint4*)dst = val;
      }
      __syncthreads();
    }
    return;
  }

#pragma unroll
  for (int m = 0; m < 4; ++m) {
#pragma unroll
    for (int n = 0; n < 4; ++n) {
#pragma unroll
      for (int r = 0; r < 4; ++r) {
        const int row = m0 + wr * 64 + m * 16 + grp * 4 + r;
        const int col = n0 + wc * 64 + n * 16 + r16;
        const int cs = col & 1023;
        const float v = (acc[m][n][r] + bp[cs]) * sc;
        if (MODE == 3) {  // seg 0/1: head-major
          const int b = row >> 11, s = row & 2047, h = cs >> 6, d = cs & 63;
          bf16* base = (bf16*)Out + (size_t)seg * NQKV;
          base[((size_t)(b * NH + h) * S_LEN + s) * HD + d] = (bf16)v;
        } else {
          ((float*)Out)[(size_t)row * N + col] = v;
        }
      }
    }
  }
}

// ------- causal flash attention: 8-wave blocks sharing the ring (24 waves/CU) ---
// 512 blocks x 8 waves (512 thr). Block = (bh, 128-row chunk c); nt = 2c+2
// staged 64-key tiles. Wave (qh = w>>1 in 0..3, kh = w&1) computes q-rows
// [128c+32qh, +32) x key-half kh of each tile -- SAME inner loop as r13, but
// the 48KB 3-slot ring is shared by 8 waves (staging per-thread halves) ->
// 3 blocks/CU = 24 waves/CU (vs r13's 12). All 512 blocks co-resident; CU k
// gets bids {k, k+256} with c = bid<256 ? 15-slot : slot -> per-CU tile sum
// constant (34). Per-wave live tiles nt_w = 2c+1+((qh-kh)>>1); diag mask iff
// (qh-kh) even, at tile nt_w-1 (verified for all 8 waves). Counted vmcnt(2)
// (T4, 2 loads/stage); stage(kt+2) after barrier; XOR-swizzle (rule #21);
// T13 defer-max; split-K combine per qh-pair in smem scratch.
__global__ __launch_bounds__(512, 6) void attn_fwd16(
    const bf16* __restrict__ Qh, const bf16* __restrict__ Kh,
    const bf16* __restrict__ Vt, bf16* __restrict__ AO) {
  __shared__ __align__(16) bf16 smem[3 * 2 * 64 * 64];  // 48KB: 3 K-slots + 3 V-slots

  const int tid = threadIdx.x;
  const int lane = tid & 63, w = tid >> 6;
  const int q31 = lane & 31, h = lane >> 5;
  const int qh = w >> 1, kh = w & 1;
  const int koff = kh << 5;

  const int bid = blockIdx.x;
  const int xcd = bid & 7;
  const int head = (bid >> 3) & 3;
  const int slot = (bid >> 5) & 7;
  const int bh = xcd * 4 + head;
  const int c = (bid < 256) ? (15 - slot) : slot;   // CU pair sums to 15

  const bf16* Qb = Qh + (size_t)bh * S_LEN * HD;
  const bf16* Kb = Kh + (size_t)bh * S_LEN * HD;
  const bf16* Vb = Vt + (size_t)bh * HD * S_LEN;

  bf16* Kl0 = smem;                  // Kl[s] = Kl0 + s*4096
  bf16* Vl0 = smem + 3 * 4096;       // Vl[s] = Vl0 + s*4096

  // staging offsets: 8KB tile = 512 x 16B; 512 threads x 1 issue (K and V each)
  const int srow = tid >> 3;                    // 0..63
  const int scolb = (tid & 7) * 16;
  const int sscol = scolb ^ ((srow & 7) << 4);
  const int stK = srow * HD + (sscol >> 1);
  const int stV = srow * S_LEN + (sscol >> 1);
  const int stL = tid * 8;
  const int swz = (q31 & 7) << 4;

#define STAGE(t, buf)                                                          \
  {                                                                            \
    gload_lds16(Kb + (size_t)(t) * 64 * HD + stK, Kl0 + (buf) * 4096 + stL);   \
    gload_lds16(Vb + (t) * 64 + stV, Vl0 + (buf) * 4096 + stL);                \
  }

  {
    const int q0 = c << 7;
    const int nt = 2 * c + 2;
    const int qg = q0 + (qh << 5) + q31;
    const int d = qh - kh;
    const int nt_w = 2 * c + 1 + (d >> 1);     // live tiles for this wave
    const bool maskw = ((d & 1) == 0);         // diag tile = nt_w-1

    bf16x8 qf[4];
#pragma unroll
    for (int ks = 0; ks < 4; ++ks)
      qf[ks] = *(const bf16x8*)&Qb[(size_t)qg * HD + ks * 16 + 8 * h];

    f32x16 acc0 = {}, acc1 = {};
    float m = -1e30f, l = 0.f;

    STAGE(0, 0)
    STAGE(1, 1)   // nt >= 2 always

    int cur = 0;
    for (int kt = 0; kt < nt; ++kt) {
      // tile kt landed when only stage(kt+1)'s 2 loads remain outstanding
      if (kt + 1 < nt) asm volatile("s_waitcnt vmcnt(2)" ::: "memory");
      else             asm volatile("s_waitcnt vmcnt(0)" ::: "memory");
      __builtin_amdgcn_s_barrier();

      if (kt + 2 < nt) {
        int nxt = cur + 2; if (nxt >= 3) nxt -= 3;
        STAGE(kt + 2, nxt)
      }

      if (kt < nt_w) {
        const char* KlC = (const char*)(Kl0 + cur * 4096);
        const char* VlC = (const char*)(Vl0 + cur * 4096);

        bf16x8 kf[4];
#pragma unroll
        for (int ks = 0; ks < 4; ++ks) {
          const int cc = (32 * ks + 16 * h) ^ swz;
          kf[ks] = *(const bf16x8*)(KlC + (koff + q31) * 128 + cc);
        }

        // ---- QK^T (32q x 32k x 64d = 4 mfma) ----
        f32x16 p0 = {};
        __builtin_amdgcn_s_setprio(1);
#pragma unroll
        for (int ks = 0; ks < 4; ++ks)
          p0 = __builtin_amdgcn_mfma_f32_32x32x16_bf16(kf[ks], qf[ks], p0, 0, 0, 0);
        __builtin_amdgcn_s_setprio(0);

        bf16x8 vf[4];
#pragma unroll
        for (int ks = 0; ks < 2; ++ks)
#pragma unroll
          for (int db = 0; db < 2; ++db) {
            const int cc = (64 * kh + 32 * ks + 16 * h) ^ swz;
            vf[ks * 2 + db] = *(const bf16x8*)(VlC + (db * 32 + q31) * 128 + cc);
          }

        // ---- causal mask (this wave's diag tile only) ----
        if (maskw && kt == nt_w - 1) {
#pragma unroll
          for (int r = 0; r < 16; ++r) {
            const int key = (kt << 6) + koff + (r & 3) + 8 * (r >> 2) + 4 * h;
            if (key > qg) p0[r] = -1e30f;
          }
        }
        // ---- tree max + cross-half shuffle ----
        float t_[16];
#pragma unroll
        for (int r = 0; r < 16; ++r) t_[r] = p0[r];
#pragma unroll
        for (int s = 8; s >= 1; s >>= 1)
#pragma unroll
          for (int r = 0; r < s; ++r) t_[r] = fmaxf(t_[r], t_[r + s]);
        const float pmax = fmaxf(t_[0], __shfl_xor(t_[0], 32));
        // ---- defer-max (T13) ----
        if (!__all(pmax - m <= 8.0f)) {
          const float mn = fmaxf(m, pmax);
          const float al = exp2f(m - mn);
          m = mn;
          l *= al;
#pragma unroll
          for (int r = 0; r < 16; ++r) { acc0[r] *= al; acc1[r] *= al; }
        }
        // ---- exp + tree sum ----
        float sv[16];
#pragma unroll
        for (int r = 0; r < 16; ++r) {
          p0[r] = exp2f(p0[r] - m);
          sv[r] = p0[r];
        }
#pragma unroll
        for (int s = 8; s >= 1; s >>= 1)
#pragma unroll
          for (int r = 0; r < s; ++r) sv[r] += sv[r + s];
        l += sv[0] + __shfl_xor(sv[0], 32);

        // ---- pack P -> 2 PV B-frags via permlane32_swap ----
        unsigned wv[8];
#pragma unroll
        for (int mm = 0; mm < 8; ++mm)
          wv[mm] = packbf(p0[2 * mm], p0[2 * mm + 1]);
        pl32swap(wv[0], wv[2]);
        pl32swap(wv[1], wv[3]);
        pl32swap(wv[4], wv[6]);
        pl32swap(wv[5], wv[7]);

        // ---- PV (2 k-steps x 2 d-halves) ----
        __builtin_amdgcn_s_setprio(1);
        {
          u32x4 pu0 = {wv[0], wv[1], wv[2], wv[3]};
          const bf16x8 pf0 = __builtin_bit_cast(bf16x8, pu0);
          acc0 = __builtin_amdgcn_mfma_f32_32x32x16_bf16(vf[0], pf0, acc0, 0, 0, 0);
          acc1 = __builtin_amdgcn_mfma_f32_32x32x16_bf16(vf[1], pf0, acc1, 0, 0, 0);
          u32x4 pu1 = {wv[4], wv[5], wv[6], wv[7]};
          const bf16x8 pf1 = __builtin_bit_cast(bf16x8, pu1);
          acc0 = __builtin_amdgcn_mfma_f32_32x32x16_bf16(vf[2], pf1, acc0, 0, 0, 0);
          acc1 = __builtin_amdgcn_mfma_f32_32x32x16_bf16(vf[3], pf1, acc1, 0, 0, 0);
        }
        __builtin_amdgcn_s_setprio(0);
      }

      ++cur; if (cur == 3) cur = 0;
    }

    // ---- split-K combine across key-half waves (per qh-group scratch) ----
    // 4 groups x 64 lanes x 34 f32 = 34.8KB over smem (ring reads all retired).
    float* s = (float*)smem + (size_t)qh * (64 * 34) + lane * 34;
    __syncthreads();
    if (kh) {
#pragma unroll
      for (int r = 0; r < 16; ++r) { s[r] = acc0[r]; s[16 + r] = acc1[r]; }
      s[32] = m;
      s[33] = l;
    }
    __syncthreads();
    if (!kh) {
      const float m1 = s[32], l1 = s[33];
      const float mn = fmaxf(m, m1);
      const float a0 = exp2f(m - mn), a1 = exp2f(m1 - mn);
      const float linv = 1.0f / (a0 * l + a1 * l1);
      const int b = bh >> 4, hh = bh & 15;
      bf16* orow = AO + ((size_t)(b * S_LEN + qg)) * DM + hh * HD;
#pragma unroll
      for (int mm = 0; mm < 4; ++mm) {
        bf16x4 ov0, ov1;
#pragma unroll
        for (int t2 = 0; t2 < 4; ++t2) {
          ov0[t2] = (bf16)((a0 * acc0[4 * mm + t2] + a1 * s[4 * mm + t2]) * linv);
          ov1[t2] = (bf16)((a0 * acc1[4 * mm + t2] + a1 * s[16 + 4 * mm + t2]) * linv);
        }
        *(bf16x4*)&orow[8 * mm + 4 * h] = ov0;
        *(bf16x4*)&orow[32 + 8 * mm + 4 * h] = ov1;
      }
    }
  }
#undef STAGE
}

// ---------------- launch ----------------
extern "C" void kernel_launch(void* const* d_in, const int* in_sizes, int n_in,
                              void* d_out, int out_size, void* d_ws, size_t ws_size,
                              hipStream_t stream) {
  const float* q  = (const float*)d_in[0];
  const float* k  = (const float*)d_in[1];
  const float* v  = (const float*)d_in[2];
  const float* Wq = (const float*)d_in[3];
  const float* bq = (const float*)d_in[4];
  const float* Wk = (const float*)d_in[5];
  const float* bk = (const float*)d_in[6];
  const float* Wv = (const float*)d_in[7];
  const float* bv = (const float*)d_in[8];
  const float* Wo = (const float*)d_in[9];
  const float* bo = (const float*)d_in[10];

  const int NTOK = 2 * S_LEN;          // 4096

  bf16* qb  = (bf16*)d_ws;             // q,k,v bf16: 3 * NQKV (consecutive)
  bf16* Wqb = qb + 3 * (size_t)NQKV;   // Wq,Wk,Wv,Wo bf16: 4 * NW (consecutive)
  bf16* Wob = Wqb + 3 * (size_t)NW;
  bf16* Qh  = Wqb + 4 * (size_t)NW;    // Qh,Kh,Vt bf16: 3 * NQKV (consecutive)
  bf16* Kh  = Qh + (size_t)NQKV;
  bf16* Vt  = Kh + (size_t)NQKV;
  bf16* AO  = Vt + (size_t)NQKV;

  const int cvt_blocks = (3 * NQKV + 4 * NW) / 8 / 256;
  cvt_all<<<cvt_blocks, 256, 0, stream>>>(q, k, v, Wq, Wk, Wv, Wo, qb);

  // fused QKV projection: M=4096, N=3072, K=1024
  gemm_bt<3><<<dim3(3 * DM / 128, NTOK / 128), 256, 0, stream>>>(
      qb, Wqb, bq, bk, bv, Qh, NTOK, 3 * DM, DM, QK_SCALE);

  // attention: 512 blocks x 512 threads (8 waves), 24 waves/CU
  attn_fwd16<<<dim3(512), 512, 0, stream>>>(Qh, Kh, Vt, AO);

  // output projection -> fp32 d_out
  gemm_bt<2><<<dim3(DM / 128, NTOK / 128), 256, 0, stream>>>(
      AO, Wqb + 3 * (size_t)NW, bo, bo, bo, d_out, NTOK, DM, DM, 1.0f);
}

// Round 17
// 116.629 us; speedup vs baseline: 1.5920x; 1.5920x over previous
//
#include <hip/hip_runtime.h>
#include <hip/hip_bf16.h>
#include <cstdint>
#include <cstddef>

typedef __bf16 bf16;
typedef __bf16 bf16x2 __attribute__((ext_vector_type(2)));
typedef __bf16 bf16x4 __attribute__((ext_vector_type(4)));
typedef __bf16 bf16x8 __attribute__((ext_vector_type(8)));
typedef float f32x4 __attribute__((ext_vector_type(4)));
typedef float f32x16 __attribute__((ext_vector_type(16)));
typedef unsigned int u32x4 __attribute__((ext_vector_type(4)));

#define S_LEN 2048
#define DM 1024
#define NH 16
#define HD 64
#define NQKV (4096 * 1024)   // tokens * DM
#define NW (1024 * 1024)
// (1/sqrt(64)) * log2(e): fold softmax scale + exp2 conversion into Q
#define QK_SCALE 0.18033688011112042f

__device__ __forceinline__ void gload_lds16(const bf16* g, bf16* l) {
  __builtin_amdgcn_global_load_lds(
      (const __attribute__((address_space(1))) void*)g,
      (__attribute__((address_space(3))) void*)l, 16, 0, 0);
}

__device__ __forceinline__ unsigned packbf(float lo, float hi) {
  bf16x2 t;
  t[0] = (bf16)lo;
  t[1] = (bf16)hi;
  return __builtin_bit_cast(unsigned, t);
}

// v_permlane32_swap_b32: new_a[l>=32] = b_old[l-32]; new_b[l<32] = a_old[l+32]
__device__ __forceinline__ void pl32swap(unsigned& a, unsigned& b) {
#if __has_builtin(__builtin_amdgcn_permlane32_swap)
  auto r = __builtin_amdgcn_permlane32_swap((int)a, (int)b, false, false);
  a = (unsigned)r[0];
  b = (unsigned)r[1];
#else
  asm volatile("v_permlane32_swap_b32 %0, %1" : "+v"(a), "+v"(b));
#endif
}

// ---------------- fused fp32 -> bf16 convert for all 7 tensors ----------------
__global__ __launch_bounds__(256) void cvt_all(
    const float* __restrict__ q, const float* __restrict__ k, const float* __restrict__ v,
    const float* __restrict__ Wq, const float* __restrict__ Wk, const float* __restrict__ Wv,
    const float* __restrict__ Wo, bf16* __restrict__ out) {
  const size_t i = ((size_t)blockIdx.x * 256 + threadIdx.x) * 8;
  const float* src;
  size_t off;
  if (i < (size_t)NQKV) { src = q; off = i; }
  else if (i < 2ull * NQKV) { src = k; off = i - NQKV; }
  else if (i < 3ull * NQKV) { src = v; off = i - 2ull * NQKV; }
  else {
    const size_t j = i - 3ull * NQKV;
    if (j < (size_t)NW) { src = Wq; off = j; }
    else if (j < 2ull * NW) { src = Wk; off = j - NW; }
    else if (j < 3ull * NW) { src = Wv; off = j - 2ull * NW; }
    else { src = Wo; off = j - 3ull * NW; }
  }
  const float4 a = *(const float4*)(src + off);
  const float4 b = *(const float4*)(src + off + 4);
  bf16x8 o;
  o[0] = (bf16)a.x; o[1] = (bf16)a.y; o[2] = (bf16)a.z; o[3] = (bf16)a.w;
  o[4] = (bf16)b.x; o[5] = (bf16)b.y; o[6] = (bf16)b.z; o[7] = (bf16)b.w;
  *(bf16x8*)(out + i) = o;
}

// ---------------- GEMM: Y[m,n] = sum_k A[m,k] * W[n,k] + bias[n] ----------------
// MODE 2: out fp32, row-major [M,N]   (final projection)
// MODE 3: fused QKV; seg = n0>>10: seg0 Q head-major*QK_SCALE, seg1 K head-major,
//         seg2 V per-head transposed [B,H,hd,S] via LDS-transposed epilogue.
template <int MODE>
__global__ __launch_bounds__(256, 3) void gemm_bt(
    const bf16* __restrict__ A, const bf16* __restrict__ W,
    const float* __restrict__ bias0, const float* __restrict__ bias1,
    const float* __restrict__ bias2, void* __restrict__ Out,
    int M, int N, int K, float scale) {
  __shared__ __align__(16) bf16 sm[2 * 128 * 64];
  bf16* Asl = sm;
  bf16* Bsl = sm + 128 * 64;
  const int tid = threadIdx.x;
  const int lane = tid & 63, w = tid >> 6;
  const int wr = w >> 1, wc = w & 1;
  const int r16 = lane & 15, grp = lane >> 4;

  // XCD swizzle: consecutive blocks within an XCD share A-panels
  int flat = blockIdx.y * gridDim.x + blockIdx.x;
  const int cpx = (gridDim.x * gridDim.y) >> 3;
  flat = (flat & 7) * cpx + (flat >> 3);
  const int m0 = (flat / gridDim.x) * 128;
  const int n0 = (flat % gridDim.x) * 128;

  const int seg = n0 >> 10;
  const bf16* Ab = (MODE == 3) ? A + (size_t)seg * NQKV : A;

  f32x4 acc[4][4] = {};

  const int nk = K >> 6;
  for (int t = 0; t < nk; ++t) {
    const int k0 = t << 6;
    __syncthreads();
#pragma unroll
    for (int j = 0; j < 4; ++j) {
      const int lin = j * 256 + tid;
      const int rr = lin >> 3;
      const int cc = (lin & 7) * 8;
      gload_lds16(&Ab[(size_t)(m0 + rr) * K + k0 + cc], &Asl[lin * 8]);
      gload_lds16(&W[(size_t)(n0 + rr) * K + k0 + cc], &Bsl[lin * 8]);
    }
    __syncthreads();
#pragma unroll
    for (int kk = 0; kk < 2; ++kk) {
      bf16x8 af[4], bfr[4];
#pragma unroll
      for (int m = 0; m < 4; ++m)
        af[m] = *(const bf16x8*)&Asl[(wr * 64 + m * 16 + r16) * 64 + kk * 32 + grp * 8];
#pragma unroll
      for (int n = 0; n < 4; ++n)
        bfr[n] = *(const bf16x8*)&Bsl[(wc * 64 + n * 16 + r16) * 64 + kk * 32 + grp * 8];
#pragma unroll
      for (int m = 0; m < 4; ++m)
#pragma unroll
        for (int n = 0; n < 4; ++n)
          acc[m][n] = __builtin_amdgcn_mfma_f32_16x16x32_bf16(af[m], bfr[n], acc[m][n], 0, 0, 0);
    }
  }

  const float* bp = (MODE == 3) ? (seg == 0 ? bias0 : (seg == 1 ? bias1 : bias2)) : bias0;
  const float sc = (MODE == 3) ? (seg == 0 ? scale : 1.0f) : scale;

  if (MODE == 3 && seg == 2) {
    // ---- V^T epilogue: transpose each wave's 64x64 quadrant via LDS ----
    __syncthreads();  // all Asl/Bsl readers done
    bf16* T = sm + w * (32 * 76);
    const int b = (m0 + wr * 64) >> 11;
    const int srow0 = (m0 + wr * 64) & 2047;
    bf16* base2 = (bf16*)Out + 2 * (size_t)NQKV;
#pragma unroll
    for (int p = 0; p < 2; ++p) {
#pragma unroll
      for (int nn = 0; nn < 2; ++nn) {
        const int n = 2 * p + nn;
#pragma unroll
        for (int mq = 0; mq < 4; ++mq)
#pragma unroll
          for (int r = 0; r < 4; ++r) {
            const int d_l = nn * 16 + r16;
            const int s_l = mq * 16 + grp * 4 + r;
            const int cs = (n0 + wc * 64 + n * 16 + r16) & 1023;
            T[d_l * 76 + s_l] = (bf16)(acc[mq][n][r] + bp[cs]);
          }
      }
      __syncthreads();
#pragma unroll
      for (int j = 0; j < 4; ++j) {
        const int d_l = j * 8 + (lane >> 3);
        const int scnk = lane & 7;
        const uint2 lo = *(const uint2*)&T[d_l * 76 + scnk * 8];
        const uint2 hi = *(const uint2*)&T[d_l * 76 + scnk * 8 + 4];
        const int cs = (n0 + wc * 64 + p * 32 + d_l) & 1023;
        const int hh = cs >> 6, dd = cs & 63;
        bf16* dst = base2 + ((size_t)(b * NH + hh) * HD + dd) * S_LEN + srow0 + scnk * 8;
        uint4 val; val.x = lo.x; val.y = lo.y; val.z = hi.x; val.w = hi.y;
        *(uint4*)dst = val;
      }
      __syncthreads();
    }
    return;
  }

#pragma unroll
  for (int m = 0; m < 4; ++m) {
#pragma unroll
    for (int n = 0; n < 4; ++n) {
#pragma unroll
      for (int r = 0; r < 4; ++r) {
        const int row = m0 + wr * 64 + m * 16 + grp * 4 + r;
        const int col = n0 + wc * 64 + n * 16 + r16;
        const int cs = col & 1023;
        const float v = (acc[m][n][r] + bp[cs]) * sc;
        if (MODE == 3) {  // seg 0/1: head-major
          const int b = row >> 11, s = row & 2047, h = cs >> 6, d = cs & 63;
          bf16* base = (bf16*)Out + (size_t)seg * NQKV;
          base[((size_t)(b * NH + h) * S_LEN + s) * HD + d] = (bf16)v;
        } else {
          ((float*)Out)[(size_t)row * N + col] = v;
        }
      }
    }
  }
}

// ------- causal flash attention: 8-wave blocks sharing the ring, 16 waves/CU ----
// (r16's kernel -- correctness HW-validated -- with the spill fixed:
//  __launch_bounds__(512,4) -> VGPR cap 128 >= ~70 needed, 2 blocks/CU.)
// 512 blocks x 8 waves. Block = (bh, 128-row chunk c); nt = 2c+2 staged tiles.
// Wave (qh = w>>1, kh = w&1): q-rows [128c+32qh,+32) x key-half kh. All 512
// blocks co-resident (256 CU x 2); CU gets bids {k, k+256} with c = 15-slot /
// slot -> per-CU tile sum constant. nt_w = 2c+1+((qh-kh)>>1); diag mask iff
// (qh-kh) even at tile nt_w-1. 3-slot shared ring, counted vmcnt(2) (T4),
// stage after barrier; XOR-swizzle (rule #21); T13 defer-max; split-K combine.
__global__ __launch_bounds__(512, 4) void attn_fwd17(
    const bf16* __restrict__ Qh, const bf16* __restrict__ Kh,
    const bf16* __restrict__ Vt, bf16* __restrict__ AO) {
  __shared__ __align__(16) bf16 smem[3 * 2 * 64 * 64];  // 48KB: 3 K + 3 V slots

  const int tid = threadIdx.x;
  const int lane = tid & 63, w = tid >> 6;
  const int q31 = lane & 31, h = lane >> 5;
  const int qh = w >> 1, kh = w & 1;
  const int koff = kh << 5;

  const int bid = blockIdx.x;
  const int xcd = bid & 7;
  const int head = (bid >> 3) & 3;
  const int slot = (bid >> 5) & 7;
  const int bh = xcd * 4 + head;
  const int c = (bid < 256) ? (15 - slot) : slot;   // CU pair sums to 15

  const bf16* Qb = Qh + (size_t)bh * S_LEN * HD;
  const bf16* Kb = Kh + (size_t)bh * S_LEN * HD;
  const bf16* Vb = Vt + (size_t)bh * HD * S_LEN;

  bf16* Kl0 = smem;                  // Kl[s] = Kl0 + s*4096
  bf16* Vl0 = smem + 3 * 4096;       // Vl[s] = Vl0 + s*4096

  // staging offsets: 8KB tile = 512 x 16B; 512 threads x 1 issue (K and V each)
  const int srow = tid >> 3;                    // 0..63
  const int scolb = (tid & 7) * 16;
  const int sscol = scolb ^ ((srow & 7) << 4);
  const int stK = srow * HD + (sscol >> 1);
  const int stV = srow * S_LEN + (sscol >> 1);
  const int stL = tid * 8;
  const int swz = (q31 & 7) << 4;

#define STAGE(t, buf)                                                          \
  {                                                                            \
    gload_lds16(Kb + (size_t)(t) * 64 * HD + stK, Kl0 + (buf) * 4096 + stL);   \
    gload_lds16(Vb + (t) * 64 + stV, Vl0 + (buf) * 4096 + stL);                \
  }

  {
    const int q0 = c << 7;
    const int nt = 2 * c + 2;
    const int qg = q0 + (qh << 5) + q31;
    const int d = qh - kh;
    const int nt_w = 2 * c + 1 + (d >> 1);     // live tiles for this wave
    const bool maskw = ((d & 1) == 0);         // diag tile = nt_w-1

    bf16x8 qf[4];
#pragma unroll
    for (int ks = 0; ks < 4; ++ks)
      qf[ks] = *(const bf16x8*)&Qb[(size_t)qg * HD + ks * 16 + 8 * h];

    f32x16 acc0 = {}, acc1 = {};
    float m = -1e30f, l = 0.f;

    STAGE(0, 0)
    STAGE(1, 1)   // nt >= 2 always

    int cur = 0;
    for (int kt = 0; kt < nt; ++kt) {
      // tile kt landed when only stage(kt+1)'s 2 loads remain outstanding
      if (kt + 1 < nt) asm volatile("s_waitcnt vmcnt(2)" ::: "memory");
      else             asm volatile("s_waitcnt vmcnt(0)" ::: "memory");
      __builtin_amdgcn_s_barrier();

      if (kt + 2 < nt) {
        int nxt = cur + 2; if (nxt >= 3) nxt -= 3;
        STAGE(kt + 2, nxt)
      }

      if (kt < nt_w) {
        const char* KlC = (const char*)(Kl0 + cur * 4096);
        const char* VlC = (const char*)(Vl0 + cur * 4096);

        bf16x8 kf[4];
#pragma unroll
        for (int ks = 0; ks < 4; ++ks) {
          const int cc = (32 * ks + 16 * h) ^ swz;
          kf[ks] = *(const bf16x8*)(KlC + (koff + q31) * 128 + cc);
        }

        // ---- QK^T (32q x 32k x 64d = 4 mfma) ----
        f32x16 p0 = {};
        __builtin_amdgcn_s_setprio(1);
#pragma unroll
        for (int ks = 0; ks < 4; ++ks)
          p0 = __builtin_amdgcn_mfma_f32_32x32x16_bf16(kf[ks], qf[ks], p0, 0, 0, 0);
        __builtin_amdgcn_s_setprio(0);

        bf16x8 vf[4];
#pragma unroll
        for (int ks = 0; ks < 2; ++ks)
#pragma unroll
          for (int db = 0; db < 2; ++db) {
            const int cc = (64 * kh + 32 * ks + 16 * h) ^ swz;
            vf[ks * 2 + db] = *(const bf16x8*)(VlC + (db * 32 + q31) * 128 + cc);
          }

        // ---- causal mask (this wave's diag tile only) ----
        if (maskw && kt == nt_w - 1) {
#pragma unroll
          for (int r = 0; r < 16; ++r) {
            const int key = (kt << 6) + koff + (r & 3) + 8 * (r >> 2) + 4 * h;
            if (key > qg) p0[r] = -1e30f;
          }
        }
        // ---- tree max + cross-half shuffle ----
        float t_[16];
#pragma unroll
        for (int r = 0; r < 16; ++r) t_[r] = p0[r];
#pragma unroll
        for (int s = 8; s >= 1; s >>= 1)
#pragma unroll
          for (int r = 0; r < s; ++r) t_[r] = fmaxf(t_[r], t_[r + s]);
        const float pmax = fmaxf(t_[0], __shfl_xor(t_[0], 32));
        // ---- defer-max (T13) ----
        if (!__all(pmax - m <= 8.0f)) {
          const float mn = fmaxf(m, pmax);
          const float al = exp2f(m - mn);
          m = mn;
          l *= al;
#pragma unroll
          for (int r = 0; r < 16; ++r) { acc0[r] *= al; acc1[r] *= al; }
        }
        // ---- exp + tree sum ----
        float sv[16];
#pragma unroll
        for (int r = 0; r < 16; ++r) {
          p0[r] = exp2f(p0[r] - m);
          sv[r] = p0[r];
        }
#pragma unroll
        for (int s = 8; s >= 1; s >>= 1)
#pragma unroll
          for (int r = 0; r < s; ++r) sv[r] += sv[r + s];
        l += sv[0] + __shfl_xor(sv[0], 32);

        // ---- pack P -> 2 PV B-frags via permlane32_swap ----
        unsigned wv[8];
#pragma unroll
        for (int mm = 0; mm < 8; ++mm)
          wv[mm] = packbf(p0[2 * mm], p0[2 * mm + 1]);
        pl32swap(wv[0], wv[2]);
        pl32swap(wv[1], wv[3]);
        pl32swap(wv[4], wv[6]);
        pl32swap(wv[5], wv[7]);

        // ---- PV (2 k-steps x 2 d-halves) ----
        __builtin_amdgcn_s_setprio(1);
        {
          u32x4 pu0 = {wv[0], wv[1], wv[2], wv[3]};
          const bf16x8 pf0 = __builtin_bit_cast(bf16x8, pu0);
          acc0 = __builtin_amdgcn_mfma_f32_32x32x16_bf16(vf[0], pf0, acc0, 0, 0, 0);
          acc1 = __builtin_amdgcn_mfma_f32_32x32x16_bf16(vf[1], pf0, acc1, 0, 0, 0);
          u32x4 pu1 = {wv[4], wv[5], wv[6], wv[7]};
          const bf16x8 pf1 = __builtin_bit_cast(bf16x8, pu1);
          acc0 = __builtin_amdgcn_mfma_f32_32x32x16_bf16(vf[2], pf1, acc0, 0, 0, 0);
          acc1 = __builtin_amdgcn_mfma_f32_32x32x16_bf16(vf[3], pf1, acc1, 0, 0, 0);
        }
        __builtin_amdgcn_s_setprio(0);
      }

      ++cur; if (cur == 3) cur = 0;
    }

    // ---- split-K combine across key-half waves (per qh-group scratch) ----
    // 4 groups x 64 lanes x 34 f32 = 34.8KB over smem (ring reads all retired).
    float* s = (float*)smem + (size_t)qh * (64 * 34) + lane * 34;
    __syncthreads();
    if (kh) {
#pragma unroll
      for (int r = 0; r < 16; ++r) { s[r] = acc0[r]; s[16 + r] = acc1[r]; }
      s[32] = m;
      s[33] = l;
    }
    __syncthreads();
    if (!kh) {
      const float m1 = s[32], l1 = s[33];
      const float mn = fmaxf(m, m1);
      const float a0 = exp2f(m - mn), a1 = exp2f(m1 - mn);
      const float linv = 1.0f / (a0 * l + a1 * l1);
      const int b = bh >> 4, hh = bh & 15;
      bf16* orow = AO + ((size_t)(b * S_LEN + qg)) * DM + hh * HD;
#pragma unroll
      for (int mm = 0; mm < 4; ++mm) {
        bf16x4 ov0, ov1;
#pragma unroll
        for (int t2 = 0; t2 < 4; ++t2) {
          ov0[t2] = (bf16)((a0 * acc0[4 * mm + t2] + a1 * s[4 * mm + t2]) * linv);
          ov1[t2] = (bf16)((a0 * acc1[4 * mm + t2] + a1 * s[16 + 4 * mm + t2]) * linv);
        }
        *(bf16x4*)&orow[8 * mm + 4 * h] = ov0;
        *(bf16x4*)&orow[32 + 8 * mm + 4 * h] = ov1;
      }
    }
  }
#undef STAGE
}

// ---------------- launch ----------------
extern "C" void kernel_launch(void* const* d_in, const int* in_sizes, int n_in,
                              void* d_out, int out_size, void* d_ws, size_t ws_size,
                              hipStream_t stream) {
  const float* q  = (const float*)d_in[0];
  const float* k  = (const float*)d_in[1];
  const float* v  = (const float*)d_in[2];
  const float* Wq = (const float*)d_in[3];
  const float* bq = (const float*)d_in[4];
  const float* Wk = (const float*)d_in[5];
  const float* bk = (const float*)d_in[6];
  const float* Wv = (const float*)d_in[7];
  const float* bv = (const float*)d_in[8];
  const float* Wo = (const float*)d_in[9];
  const float* bo = (const float*)d_in[10];

  const int NTOK = 2 * S_LEN;          // 4096

  bf16* qb  = (bf16*)d_ws;             // q,k,v bf16: 3 * NQKV (consecutive)
  bf16* Wqb = qb + 3 * (size_t)NQKV;   // Wq,Wk,Wv,Wo bf16: 4 * NW (consecutive)
  bf16* Wob = Wqb + 3 * (size_t)NW;
  bf16* Qh  = Wqb + 4 * (size_t)NW;    // Qh,Kh,Vt bf16: 3 * NQKV (consecutive)
  bf16* Kh  = Qh + (size_t)NQKV;
  bf16* Vt  = Kh + (size_t)NQKV;
  bf16* AO  = Vt + (size_t)NQKV;

  const int cvt_blocks = (3 * NQKV + 4 * NW) / 8 / 256;
  cvt_all<<<cvt_blocks, 256, 0, stream>>>(q, k, v, Wq, Wk, Wv, Wo, qb);

  // fused QKV projection: M=4096, N=3072, K=1024
  gemm_bt<3><<<dim3(3 * DM / 128, NTOK / 128), 256, 0, stream>>>(
      qb, Wqb, bq, bk, bv, Qh, NTOK, 3 * DM, DM, QK_SCALE);

  // attention: 512 blocks x 512 threads (8 waves), 16 waves/CU, no spill
  attn_fwd17<<<dim3(512), 512, 0, stream>>>(Qh, Kh, Vt, AO);

  // output projection -> fp32 d_out
  gemm_bt<2><<<dim3(DM / 128, NTOK / 128), 256, 0, stream>>>(
      AO, Wob, bo, bo, bo, d_out, NTOK, DM, DM, 1.0f);
}

// Round 18
// 113.913 us; speedup vs baseline: 1.6300x; 1.0238x over previous
//
#include <hip/hip_runtime.h>
#include <hip/hip_bf16.h>
#include <cstdint>
#include <cstddef>

typedef __bf16 bf16;
typedef __bf16 bf16x2 __attribute__((ext_vector_type(2)));
typedef __bf16 bf16x4 __attribute__((ext_vector_type(4)));
typedef __bf16 bf16x8 __attribute__((ext_vector_type(8)));
typedef float f32x4 __attribute__((ext_vector_type(4)));
typedef float f32x16 __attribute__((ext_vector_type(16)));
typedef unsigned int u32x4 __attribute__((ext_vector_type(4)));

#define S_LEN 2048
#define DM 1024
#define NH 16
#define HD 64
#define NQKV (4096 * 1024)   // tokens * DM
#define NW (1024 * 1024)
// (1/sqrt(64)) * log2(e): fold softmax scale + exp2 conversion into Q
#define QK_SCALE 0.18033688011112042f

__device__ __forceinline__ void gload_lds16(const bf16* g, bf16* l) {
  __builtin_amdgcn_global_load_lds(
      (const __attribute__((address_space(1))) void*)g,
      (__attribute__((address_space(3))) void*)l, 16, 0, 0);
}

__device__ __forceinline__ unsigned packbf(float lo, float hi) {
  bf16x2 t;
  t[0] = (bf16)lo;
  t[1] = (bf16)hi;
  return __builtin_bit_cast(unsigned, t);
}

// v_permlane32_swap_b32: new_a[l>=32] = b_old[l-32]; new_b[l<32] = a_old[l+32]
__device__ __forceinline__ void pl32swap(unsigned& a, unsigned& b) {
#if __has_builtin(__builtin_amdgcn_permlane32_swap)
  auto r = __builtin_amdgcn_permlane32_swap((int)a, (int)b, false, false);
  a = (unsigned)r[0];
  b = (unsigned)r[1];
#else
  asm volatile("v_permlane32_swap_b32 %0, %1" : "+v"(a), "+v"(b));
#endif
}

// ---------------- fused fp32 -> bf16 convert for all 7 tensors ----------------
__global__ __launch_bounds__(256) void cvt_all(
    const float* __restrict__ q, const float* __restrict__ k, const float* __restrict__ v,
    const float* __restrict__ Wq, const float* __restrict__ Wk, const float* __restrict__ Wv,
    const float* __restrict__ Wo, bf16* __restrict__ out) {
  const size_t i = ((size_t)blockIdx.x * 256 + threadIdx.x) * 8;
  const float* src;
  size_t off;
  if (i < (size_t)NQKV) { src = q; off = i; }
  else if (i < 2ull * NQKV) { src = k; off = i - NQKV; }
  else if (i < 3ull * NQKV) { src = v; off = i - 2ull * NQKV; }
  else {
    const size_t j = i - 3ull * NQKV;
    if (j < (size_t)NW) { src = Wq; off = j; }
    else if (j < 2ull * NW) { src = Wk; off = j - NW; }
    else if (j < 3ull * NW) { src = Wv; off = j - 2ull * NW; }
    else { src = Wo; off = j - 3ull * NW; }
  }
  const float4 a = *(const float4*)(src + off);
  const float4 b = *(const float4*)(src + off + 4);
  bf16x8 o;
  o[0] = (bf16)a.x; o[1] = (bf16)a.y; o[2] = (bf16)a.z; o[3] = (bf16)a.w;
  o[4] = (bf16)b.x; o[5] = (bf16)b.y; o[6] = (bf16)b.z; o[7] = (bf16)b.w;
  *(bf16x8*)(out + i) = o;
}

// ---------------- GEMM: Y[m,n] = sum_k A[m,k] * W[n,k] + bias[n] ----------------
// NEW: single-barrier double-buffered K-loop (catalog "minimum 2-phase", T3):
//   prologue STAGE(0); barrier;
//   iter t: STAGE(t+1 -> buf^1); compute(t) from buf; __syncthreads(); cur^=1
// Race ledger: buf^1's readers (iter t-1) all retired before iter t-1's end
// barrier, and STAGE(t+1) is issued after it. End-of-iter syncthreads drains
// vmcnt (compiler emits the waitcnt) AFTER ~32 MFMA -> staging latency hidden.
// One barrier per K-step (was two + early drain).
// MODE 2: out fp32, row-major [M,N]   (final projection)
// MODE 3: fused QKV; seg = n0>>10: seg0 Q head-major*QK_SCALE, seg1 K head-major,
//         seg2 V per-head transposed [B,H,hd,S] via LDS-transposed epilogue.
template <int MODE>
__global__ __launch_bounds__(256, 3) void gemm_bt(
    const bf16* __restrict__ A, const bf16* __restrict__ W,
    const float* __restrict__ bias0, const float* __restrict__ bias1,
    const float* __restrict__ bias2, void* __restrict__ Out,
    int M, int N, int K, float scale) {
  __shared__ __align__(16) bf16 sm[2 * 2 * 128 * 64];  // 2 bufs x (A 16KB + B 16KB)
  const int tid = threadIdx.x;
  const int lane = tid & 63, w = tid >> 6;
  const int wr = w >> 1, wc = w & 1;
  const int r16 = lane & 15, grp = lane >> 4;

  // XCD swizzle: consecutive blocks within an XCD share A-panels
  int flat = blockIdx.y * gridDim.x + blockIdx.x;
  const int cpx = (gridDim.x * gridDim.y) >> 3;
  flat = (flat & 7) * cpx + (flat >> 3);
  const int m0 = (flat / gridDim.x) * 128;
  const int n0 = (flat % gridDim.x) * 128;

  const int seg = n0 >> 10;
  const bf16* Ab = (MODE == 3) ? A + (size_t)seg * NQKV : A;

  f32x4 acc[4][4] = {};

  // staging offsets (per thread: 4 A-loads + 4 B-loads of 16B)
  int stG[4], stL[4];
#pragma unroll
  for (int j = 0; j < 4; ++j) {
    const int lin = j * 256 + tid;
    stG[j] = (lin >> 3) * K + (lin & 7) * 8;   // + m0/n0*K + k0
    stL[j] = lin * 8;
  }

#define GSTAGE(t, buf)                                                         \
  {                                                                            \
    const int k0_ = (t) << 6;                                                  \
    bf16* as_ = sm + (buf) * 16384;                                            \
    bf16* bs_ = as_ + 8192;                                                    \
    _Pragma("unroll") for (int j = 0; j < 4; ++j) {                            \
      gload_lds16(&Ab[(size_t)m0 * K + k0_ + stG[j]], &as_[stL[j]]);           \
      gload_lds16(&W[(size_t)n0 * K + k0_ + stG[j]], &bs_[stL[j]]);            \
    }                                                                          \
  }

  const int nk = K >> 6;
  GSTAGE(0, 0)
  __syncthreads();  // drain stage(0)

  int cur = 0;
  for (int t = 0; t < nk; ++t) {
    if (t + 1 < nk) GSTAGE(t + 1, cur ^ 1)
    const bf16* Asl = sm + cur * 16384;
    const bf16* Bsl = Asl + 8192;
#pragma unroll
    for (int kk = 0; kk < 2; ++kk) {
      bf16x8 af[4], bfr[4];
#pragma unroll
      for (int m = 0; m < 4; ++m)
        af[m] = *(const bf16x8*)&Asl[(wr * 64 + m * 16 + r16) * 64 + kk * 32 + grp * 8];
#pragma unroll
      for (int n = 0; n < 4; ++n)
        bfr[n] = *(const bf16x8*)&Bsl[(wc * 64 + n * 16 + r16) * 64 + kk * 32 + grp * 8];
#pragma unroll
      for (int m = 0; m < 4; ++m)
#pragma unroll
        for (int n = 0; n < 4; ++n)
          acc[m][n] = __builtin_amdgcn_mfma_f32_16x16x32_bf16(af[m], bfr[n], acc[m][n], 0, 0, 0);
    }
    __syncthreads();  // drains vmcnt (stage t+1 landed) + read-retire fence
    cur ^= 1;
  }
#undef GSTAGE

  const float* bp = (MODE == 3) ? (seg == 0 ? bias0 : (seg == 1 ? bias1 : bias2)) : bias0;
  const float sc = (MODE == 3) ? (seg == 0 ? scale : 1.0f) : scale;

  if (MODE == 3 && seg == 2) {
    // ---- V^T epilogue: transpose each wave's 64x64 quadrant via LDS ----
    bf16* T = sm + w * (32 * 76);
    const int b = (m0 + wr * 64) >> 11;
    const int srow0 = (m0 + wr * 64) & 2047;
    bf16* base2 = (bf16*)Out + 2 * (size_t)NQKV;
#pragma unroll
    for (int p = 0; p < 2; ++p) {
#pragma unroll
      for (int nn = 0; nn < 2; ++nn) {
        const int n = 2 * p + nn;
#pragma unroll
        for (int mq = 0; mq < 4; ++mq)
#pragma unroll
          for (int r = 0; r < 4; ++r) {
            const int d_l = nn * 16 + r16;
            const int s_l = mq * 16 + grp * 4 + r;
            const int cs = (n0 + wc * 64 + n * 16 + r16) & 1023;
            T[d_l * 76 + s_l] = (bf16)(acc[mq][n][r] + bp[cs]);
          }
      }
      __syncthreads();
#pragma unroll
      for (int j = 0; j < 4; ++j) {
        const int d_l = j * 8 + (lane >> 3);
        const int scnk = lane & 7;
        const uint2 lo = *(const uint2*)&T[d_l * 76 + scnk * 8];
        const uint2 hi = *(const uint2*)&T[d_l * 76 + scnk * 8 + 4];
        const int cs = (n0 + wc * 64 + p * 32 + d_l) & 1023;
        const int hh = cs >> 6, dd = cs & 63;
        bf16* dst = base2 + ((size_t)(b * NH + hh) * HD + dd) * S_LEN + srow0 + scnk * 8;
        uint4 val; val.x = lo.x; val.y = lo.y; val.z = hi.x; val.w = hi.y;
        *(uint4*)dst = val;
      }
      __syncthreads();
    }
    return;
  }

#pragma unroll
  for (int m = 0; m < 4; ++m) {
#pragma unroll
    for (int n = 0; n < 4; ++n) {
#pragma unroll
      for (int r = 0; r < 4; ++r) {
        const int row = m0 + wr * 64 + m * 16 + grp * 4 + r;
        const int col = n0 + wc * 64 + n * 16 + r16;
        const int cs = col & 1023;
        const float v = (acc[m][n][r] + bp[cs]) * sc;
        if (MODE == 3) {  // seg 0/1: head-major
          const int b = row >> 11, s = row & 2047, h = cs >> 6, d = cs & 63;
          bf16* base = (bf16*)Out + (size_t)seg * NQKV;
          base[((size_t)(b * NH + h) * S_LEN + s) * HD + d] = (bf16)v;
        } else {
          ((float*)Out)[(size_t)row * N + col] = v;
        }
      }
    }
  }
}

// ---------------- causal flash attention: single-chunk blocks, 3/CU ------------
// (round-13 structure, session best: 45.0us, Occ 25.4%)
__global__ __launch_bounds__(256, 3) void attn_fwd13(
    const bf16* __restrict__ Qh, const bf16* __restrict__ Kh,
    const bf16* __restrict__ Vt, bf16* __restrict__ AO) {
  __shared__ __align__(16) bf16 Kl[3][64 * 64];
  __shared__ __align__(16) bf16 Vl[3][64 * 64];

  const int tid = threadIdx.x;
  const int lane = tid & 63, w = tid >> 6;
  const int q31 = lane & 31, h = lane >> 5;
  const int qh = w >> 1, kh = w & 1;
  const int koff = kh << 5;

  const int bid = blockIdx.x;
  const int xcd = bid & 7;
  const int within = bid >> 3;
  const int bh = xcd * 4 + (within & 3);
  const int c = 31 - (within >> 2);

  const bf16* Qb = Qh + (size_t)bh * S_LEN * HD;
  const bf16* Kb = Kh + (size_t)bh * S_LEN * HD;
  const bf16* Vb = Vt + (size_t)bh * HD * S_LEN;

  int stK[2], stV[2], stL[2];
#pragma unroll
  for (int i = 0; i < 2; ++i) {
    const int lin = i * 256 + tid;
    const int row = lin >> 3;
    const int colb = (lin & 7) * 16;
    const int scol = colb ^ ((row & 7) << 4);
    stK[i] = row * HD + (scol >> 1);
    stV[i] = row * S_LEN + (scol >> 1);
    stL[i] = lin * 8;
  }
  const int swz = (q31 & 7) << 4;

#define STAGE(t, buf)                                                          \
  {                                                                            \
    const bf16* kb_ = Kb + (size_t)(t) * 64 * HD;                              \
    const bf16* vb_ = Vb + (t) * 64;                                           \
    _Pragma("unroll") for (int i = 0; i < 2; ++i) {                            \
      gload_lds16(kb_ + stK[i], &Kl[buf][stL[i]]);                             \
      gload_lds16(vb_ + stV[i], &Vl[buf][stL[i]]);                             \
    }                                                                          \
  }

  {
    const int q0 = c << 6;
    const int nt = c + 1;
    const int q0w = q0 + (qh << 5);
    const int qg = q0w + q31;
    const int nt_w = (w == 1) ? nt - 1 : nt;
    const bool maskw = (w == 0) || (w == 3);

    bf16x8 qf[4];
#pragma unroll
    for (int ks = 0; ks < 4; ++ks)
      qf[ks] = *(const bf16x8*)&Qb[(size_t)qg * HD + ks * 16 + 8 * h];

    f32x16 acc0 = {}, acc1 = {};
    float m = -1e30f, l = 0.f;

    STAGE(0, 0)
    if (nt > 1) STAGE(1, 1)

    int cur = 0;
    for (int kt = 0; kt < nt; ++kt) {
      if (kt + 1 < nt) asm volatile("s_waitcnt vmcnt(4)" ::: "memory");
      else             asm volatile("s_waitcnt vmcnt(0)" ::: "memory");
      __builtin_amdgcn_s_barrier();

      if (kt + 2 < nt) {
        int nxt = cur + 2; if (nxt >= 3) nxt -= 3;
        STAGE(kt + 2, nxt)
      }

      if (kt < nt_w) {
        const bf16* KlC = &Kl[cur][0];
        const bf16* VlC = &Vl[cur][0];

        bf16x8 kf[4];
#pragma unroll
        for (int ks = 0; ks < 4; ++ks) {
          const int cc = (32 * ks + 16 * h) ^ swz;
          kf[ks] = *(const bf16x8*)((const char*)KlC + (koff + q31) * 128 + cc);
        }

        f32x16 p0 = {};
        __builtin_amdgcn_s_setprio(1);
#pragma unroll
        for (int ks = 0; ks < 4; ++ks)
          p0 = __builtin_amdgcn_mfma_f32_32x32x16_bf16(kf[ks], qf[ks], p0, 0, 0, 0);
        __builtin_amdgcn_s_setprio(0);

        bf16x8 vf[4];
#pragma unroll
        for (int ks = 0; ks < 2; ++ks)
#pragma unroll
          for (int db = 0; db < 2; ++db) {
            const int cc = (64 * kh + 32 * ks + 16 * h) ^ swz;
            vf[ks * 2 + db] =
                *(const bf16x8*)((const char*)VlC + (db * 32 + q31) * 128 + cc);
          }

        if (maskw && kt == nt - 1) {
#pragma unroll
          for (int r = 0; r < 16; ++r) {
            const int key = (kt << 6) + koff + (r & 3) + 8 * (r >> 2) + 4 * h;
            if (key > qg) p0[r] = -1e30f;
          }
        }
        float t_[16];
#pragma unroll
        for (int r = 0; r < 16; ++r) t_[r] = p0[r];
#pragma unroll
        for (int s = 8; s >= 1; s >>= 1)
#pragma unroll
          for (int r = 0; r < s; ++r) t_[r] = fmaxf(t_[r], t_[r + s]);
        const float pmax = fmaxf(t_[0], __shfl_xor(t_[0], 32));
        if (!__all(pmax - m <= 8.0f)) {
          const float mn = fmaxf(m, pmax);
          const float al = exp2f(m - mn);
          m = mn;
          l *= al;
#pragma unroll
          for (int r = 0; r < 16; ++r) { acc0[r] *= al; acc1[r] *= al; }
        }
        float sv[16];
#pragma unroll
        for (int r = 0; r < 16; ++r) {
          p0[r] = exp2f(p0[r] - m);
          sv[r] = p0[r];
        }
#pragma unroll
        for (int s = 8; s >= 1; s >>= 1)
#pragma unroll
          for (int r = 0; r < s; ++r) sv[r] += sv[r + s];
        l += sv[0] + __shfl_xor(sv[0], 32);

        unsigned wv[8];
#pragma unroll
        for (int mm = 0; mm < 8; ++mm)
          wv[mm] = packbf(p0[2 * mm], p0[2 * mm + 1]);
        pl32swap(wv[0], wv[2]);
        pl32swap(wv[1], wv[3]);
        pl32swap(wv[4], wv[6]);
        pl32swap(wv[5], wv[7]);

        __builtin_amdgcn_s_setprio(1);
        {
          u32x4 pu0 = {wv[0], wv[1], wv[2], wv[3]};
          const bf16x8 pf0 = __builtin_bit_cast(bf16x8, pu0);
          acc0 = __builtin_amdgcn_mfma_f32_32x32x16_bf16(vf[0], pf0, acc0, 0, 0, 0);
          acc1 = __builtin_amdgcn_mfma_f32_32x32x16_bf16(vf[1], pf0, acc1, 0, 0, 0);
          u32x4 pu1 = {wv[4], wv[5], wv[6], wv[7]};
          const bf16x8 pf1 = __builtin_bit_cast(bf16x8, pu1);
          acc0 = __builtin_amdgcn_mfma_f32_32x32x16_bf16(vf[2], pf1, acc0, 0, 0, 0);
          acc1 = __builtin_amdgcn_mfma_f32_32x32x16_bf16(vf[3], pf1, acc1, 0, 0, 0);
        }
        __builtin_amdgcn_s_setprio(0);
      }

      ++cur; if (cur == 3) cur = 0;
    }

    // ---- split-K combine across key-half waves (scratch = Kl area) ----
    float* scr = (float*)&Kl[0][0];
    float* s = scr + (size_t)qh * (64 * 34) + lane * 34;
    __syncthreads();
    if (kh) {
#pragma unroll
      for (int r = 0; r < 16; ++r) { s[r] = acc0[r]; s[16 + r] = acc1[r]; }
      s[32] = m;
      s[33] = l;
    }
    __syncthreads();
    if (!kh) {
      const float m1 = s[32], l1 = s[33];
      const float mn = fmaxf(m, m1);
      const float a0 = exp2f(m - mn), a1 = exp2f(m1 - mn);
      const float linv = 1.0f / (a0 * l + a1 * l1);
      const int b = bh >> 4, hh = bh & 15;
      bf16* orow = AO + ((size_t)(b * S_LEN + qg)) * DM + hh * HD;
#pragma unroll
      for (int mm = 0; mm < 4; ++mm) {
        bf16x4 ov0, ov1;
#pragma unroll
        for (int t2 = 0; t2 < 4; ++t2) {
          ov0[t2] = (bf16)((a0 * acc0[4 * mm + t2] + a1 * s[4 * mm + t2]) * linv);
          ov1[t2] = (bf16)((a0 * acc1[4 * mm + t2] + a1 * s[16 + 4 * mm + t2]) * linv);
        }
        *(bf16x4*)&orow[8 * mm + 4 * h] = ov0;
        *(bf16x4*)&orow[32 + 8 * mm + 4 * h] = ov1;
      }
    }
  }
#undef STAGE
}

// ---------------- launch ----------------
extern "C" void kernel_launch(void* const* d_in, const int* in_sizes, int n_in,
                              void* d_out, int out_size, void* d_ws, size_t ws_size,
                              hipStream_t stream) {
  const float* q  = (const float*)d_in[0];
  const float* k  = (const float*)d_in[1];
  const float* v  = (const float*)d_in[2];
  const float* Wq = (const float*)d_in[3];
  const float* bq = (const float*)d_in[4];
  const float* Wk = (const float*)d_in[5];
  const float* bk = (const float*)d_in[6];
  const float* Wv = (const float*)d_in[7];
  const float* bv = (const float*)d_in[8];
  const float* Wo = (const float*)d_in[9];
  const float* bo = (const float*)d_in[10];

  const int NTOK = 2 * S_LEN;          // 4096

  bf16* qb  = (bf16*)d_ws;             // q,k,v bf16: 3 * NQKV (consecutive)
  bf16* Wqb = qb + 3 * (size_t)NQKV;   // Wq,Wk,Wv,Wo bf16: 4 * NW (consecutive)
  bf16* Wob = Wqb + 3 * (size_t)NW;
  bf16* Qh  = Wqb + 4 * (size_t)NW;    // Qh,Kh,Vt bf16: 3 * NQKV (consecutive)
  bf16* Kh  = Qh + (size_t)NQKV;
  bf16* Vt  = Kh + (size_t)NQKV;
  bf16* AO  = Vt + (size_t)NQKV;

  const int cvt_blocks = (3 * NQKV + 4 * NW) / 8 / 256;
  cvt_all<<<cvt_blocks, 256, 0, stream>>>(q, k, v, Wq, Wk, Wv, Wo, qb);

  // fused QKV projection: M=4096, N=3072, K=1024
  gemm_bt<3><<<dim3(3 * DM / 128, NTOK / 128), 256, 0, stream>>>(
      qb, Wqb, bq, bk, bv, Qh, NTOK, 3 * DM, DM, QK_SCALE);

  // attention: 1024 single-chunk blocks x 256 threads, heavy-first, 3/CU
  attn_fwd13<<<dim3(1024), 256, 0, stream>>>(Qh, Kh, Vt, AO);

  // output projection -> fp32 d_out
  gemm_bt<2><<<dim3(DM / 128, NTOK / 128), 256, 0, stream>>>(
      AO, Wob, bo, bo, bo, d_out, NTOK, DM, DM, 1.0f);
}

// Round 19
// 112.080 us; speedup vs baseline: 1.6566x; 1.0163x over previous
//
#include <hip/hip_runtime.h>
#include <hip/hip_bf16.h>
#include <cstdint>
#include <cstddef>

typedef __bf16 bf16;
typedef __bf16 bf16x2 __attribute__((ext_vector_type(2)));
typedef __bf16 bf16x4 __attribute__((ext_vector_type(4)));
typedef __bf16 bf16x8 __attribute__((ext_vector_type(8)));
typedef float f32x4 __attribute__((ext_vector_type(4)));
typedef float f32x16 __attribute__((ext_vector_type(16)));
typedef unsigned int u32x4 __attribute__((ext_vector_type(4)));

#define S_LEN 2048
#define DM 1024
#define NH 16
#define HD 64
#define NQKV (4096 * 1024)   // tokens * DM
#define NW (1024 * 1024)
// (1/sqrt(64)) * log2(e): fold softmax scale + exp2 conversion into Q
#define QK_SCALE 0.18033688011112042f

__device__ __forceinline__ void gload_lds16(const bf16* g, bf16* l) {
  __builtin_amdgcn_global_load_lds(
      (const __attribute__((address_space(1))) void*)g,
      (__attribute__((address_space(3))) void*)l, 16, 0, 0);
}

__device__ __forceinline__ unsigned packbf(float lo, float hi) {
  bf16x2 t;
  t[0] = (bf16)lo;
  t[1] = (bf16)hi;
  return __builtin_bit_cast(unsigned, t);
}

// v_permlane32_swap_b32: new_a[l>=32] = b_old[l-32]; new_b[l<32] = a_old[l+32]
__device__ __forceinline__ void pl32swap(unsigned& a, unsigned& b) {
#if __has_builtin(__builtin_amdgcn_permlane32_swap)
  auto r = __builtin_amdgcn_permlane32_swap((int)a, (int)b, false, false);
  a = (unsigned)r[0];
  b = (unsigned)r[1];
#else
  asm volatile("v_permlane32_swap_b32 %0, %1" : "+v"(a), "+v"(b));
#endif
}

// ---------------- fused fp32 -> bf16 convert for all 7 tensors ----------------
__global__ __launch_bounds__(256) void cvt_all(
    const float* __restrict__ q, const float* __restrict__ k, const float* __restrict__ v,
    const float* __restrict__ Wq, const float* __restrict__ Wk, const float* __restrict__ Wv,
    const float* __restrict__ Wo, bf16* __restrict__ out) {
  const size_t i = ((size_t)blockIdx.x * 256 + threadIdx.x) * 8;
  const float* src;
  size_t off;
  if (i < (size_t)NQKV) { src = q; off = i; }
  else if (i < 2ull * NQKV) { src = k; off = i - NQKV; }
  else if (i < 3ull * NQKV) { src = v; off = i - 2ull * NQKV; }
  else {
    const size_t j = i - 3ull * NQKV;
    if (j < (size_t)NW) { src = Wq; off = j; }
    else if (j < 2ull * NW) { src = Wk; off = j - NW; }
    else if (j < 3ull * NW) { src = Wv; off = j - 2ull * NW; }
    else { src = Wo; off = j - 3ull * NW; }
  }
  const float4 a = *(const float4*)(src + off);
  const float4 b = *(const float4*)(src + off + 4);
  bf16x8 o;
  o[0] = (bf16)a.x; o[1] = (bf16)a.y; o[2] = (bf16)a.z; o[3] = (bf16)a.w;
  o[4] = (bf16)b.x; o[5] = (bf16)b.y; o[6] = (bf16)b.z; o[7] = (bf16)b.w;
  *(bf16x8*)(out + i) = o;
}

// ---------------- GEMM: Y[m,n] = sum_k A[m,k] * W[n,k] + bias[n] ----------------
// Single-barrier double-buffered K-loop (r18 proven) with BK=32:
// 2 bufs x (A 8KB + B 8KB) = 32KB LDS -> 3 blocks/CU, full 768-block grid
// co-resident (zero tail epoch) + m114 wave-overlap. 32 iters x 16 MFMA.
// Race ledger (as r18): stage(t+1)->buf^1 issued after prior syncthreads
// (buf^1's readers retired there); end-of-iter syncthreads drains vmcnt.
// MODE 2: out fp32, row-major [M,N]   (final projection)
// MODE 3: fused QKV; seg = n0>>10: seg0 Q head-major*QK_SCALE, seg1 K head-major,
//         seg2 V per-head transposed [B,H,hd,S] via LDS-transposed epilogue.
template <int MODE>
__global__ __launch_bounds__(256, 3) void gemm_bt(
    const bf16* __restrict__ A, const bf16* __restrict__ W,
    const float* __restrict__ bias0, const float* __restrict__ bias1,
    const float* __restrict__ bias2, void* __restrict__ Out,
    int M, int N, int K, float scale) {
  __shared__ __align__(16) bf16 sm[2 * 2 * 128 * 32];  // 2 bufs x (A 8KB + B 8KB)
  const int tid = threadIdx.x;
  const int lane = tid & 63, w = tid >> 6;
  const int wr = w >> 1, wc = w & 1;
  const int r16 = lane & 15, grp = lane >> 4;

  // XCD swizzle: consecutive blocks within an XCD share A-panels
  int flat = blockIdx.y * gridDim.x + blockIdx.x;
  const int cpx = (gridDim.x * gridDim.y) >> 3;
  flat = (flat & 7) * cpx + (flat >> 3);
  const int m0 = (flat / gridDim.x) * 128;
  const int n0 = (flat % gridDim.x) * 128;

  const int seg = n0 >> 10;
  const bf16* Ab = (MODE == 3) ? A + (size_t)seg * NQKV : A;

  f32x4 acc[4][4] = {};

  // staging offsets: per thread 2 A-loads + 2 B-loads of 16B (128x32 tile)
  int stG[2], stL[2];
#pragma unroll
  for (int j = 0; j < 2; ++j) {
    const int lin = j * 256 + tid;             // 0..511
    stG[j] = (lin >> 2) * K + (lin & 3) * 8;   // row 0..127, k-off 0..24
    stL[j] = lin * 8;
  }

#define GSTAGE(t, buf)                                                         \
  {                                                                            \
    const int k0_ = (t) << 5;                                                  \
    bf16* as_ = sm + (buf) * 8192;                                             \
    bf16* bs_ = as_ + 4096;                                                    \
    _Pragma("unroll") for (int j = 0; j < 2; ++j) {                            \
      gload_lds16(&Ab[(size_t)m0 * K + k0_ + stG[j]], &as_[stL[j]]);           \
      gload_lds16(&W[(size_t)n0 * K + k0_ + stG[j]], &bs_[stL[j]]);            \
    }                                                                          \
  }

  const int nk = K >> 5;
  GSTAGE(0, 0)
  __syncthreads();  // drain stage(0)

  int cur = 0;
  for (int t = 0; t < nk; ++t) {
    if (t + 1 < nk) GSTAGE(t + 1, cur ^ 1)
    const bf16* Asl = sm + cur * 8192;
    const bf16* Bsl = Asl + 4096;
    {
      bf16x8 af[4], bfr[4];
#pragma unroll
      for (int m = 0; m < 4; ++m)
        af[m] = *(const bf16x8*)&Asl[(wr * 64 + m * 16 + r16) * 32 + grp * 8];
#pragma unroll
      for (int n = 0; n < 4; ++n)
        bfr[n] = *(const bf16x8*)&Bsl[(wc * 64 + n * 16 + r16) * 32 + grp * 8];
#pragma unroll
      for (int m = 0; m < 4; ++m)
#pragma unroll
        for (int n = 0; n < 4; ++n)
          acc[m][n] = __builtin_amdgcn_mfma_f32_16x16x32_bf16(af[m], bfr[n], acc[m][n], 0, 0, 0);
    }
    __syncthreads();  // drains vmcnt (stage t+1 landed) + read-retire fence
    cur ^= 1;
  }
#undef GSTAGE

  const float* bp = (MODE == 3) ? (seg == 0 ? bias0 : (seg == 1 ? bias1 : bias2)) : bias0;
  const float sc = (MODE == 3) ? (seg == 0 ? scale : 1.0f) : scale;

  if (MODE == 3 && seg == 2) {
    // ---- V^T epilogue: transpose each wave's 64x64 quadrant via LDS ----
    // T = per-wave 32x76 bf16 (4 waves x 4864B = 19KB <= 32KB smem)
    bf16* T = sm + w * (32 * 76);
    const int b = (m0 + wr * 64) >> 11;
    const int srow0 = (m0 + wr * 64) & 2047;
    bf16* base2 = (bf16*)Out + 2 * (size_t)NQKV;
#pragma unroll
    for (int p = 0; p < 2; ++p) {
#pragma unroll
      for (int nn = 0; nn < 2; ++nn) {
        const int n = 2 * p + nn;
#pragma unroll
        for (int mq = 0; mq < 4; ++mq)
#pragma unroll
          for (int r = 0; r < 4; ++r) {
            const int d_l = nn * 16 + r16;
            const int s_l = mq * 16 + grp * 4 + r;
            const int cs = (n0 + wc * 64 + n * 16 + r16) & 1023;
            T[d_l * 76 + s_l] = (bf16)(acc[mq][n][r] + bp[cs]);
          }
      }
      __syncthreads();
#pragma unroll
      for (int j = 0; j < 4; ++j) {
        const int d_l = j * 8 + (lane >> 3);
        const int scnk = lane & 7;
        const uint2 lo = *(const uint2*)&T[d_l * 76 + scnk * 8];
        const uint2 hi = *(const uint2*)&T[d_l * 76 + scnk * 8 + 4];
        const int cs = (n0 + wc * 64 + p * 32 + d_l) & 1023;
        const int hh = cs >> 6, dd = cs & 63;
        bf16* dst = base2 + ((size_t)(b * NH + hh) * HD + dd) * S_LEN + srow0 + scnk * 8;
        uint4 val; val.x = lo.x; val.y = lo.y; val.z = hi.x; val.w = hi.y;
        *(uint4*)dst = val;
      }
      __syncthreads();
    }
    return;
  }

#pragma unroll
  for (int m = 0; m < 4; ++m) {
#pragma unroll
    for (int n = 0; n < 4; ++n) {
#pragma unroll
      for (int r = 0; r < 4; ++r) {
        const int row = m0 + wr * 64 + m * 16 + grp * 4 + r;
        const int col = n0 + wc * 64 + n * 16 + r16;
        const int cs = col & 1023;
        const float v = (acc[m][n][r] + bp[cs]) * sc;
        if (MODE == 3) {  // seg 0/1: head-major
          const int b = row >> 11, s = row & 2047, h = cs >> 6, d = cs & 63;
          bf16* base = (bf16*)Out + (size_t)seg * NQKV;
          base[((size_t)(b * NH + h) * S_LEN + s) * HD + d] = (bf16)v;
        } else {
          ((float*)Out)[(size_t)row * N + col] = v;
        }
      }
    }
  }
}

// ---------------- causal flash attention: single-chunk blocks, 3/CU ------------
// (round-13 structure, session best: 45.0us, Occ 25.4%)
__global__ __launch_bounds__(256, 3) void attn_fwd13(
    const bf16* __restrict__ Qh, const bf16* __restrict__ Kh,
    const bf16* __restrict__ Vt, bf16* __restrict__ AO) {
  __shared__ __align__(16) bf16 Kl[3][64 * 64];
  __shared__ __align__(16) bf16 Vl[3][64 * 64];

  const int tid = threadIdx.x;
  const int lane = tid & 63, w = tid >> 6;
  const int q31 = lane & 31, h = lane >> 5;
  const int qh = w >> 1, kh = w & 1;
  const int koff = kh << 5;

  const int bid = blockIdx.x;
  const int xcd = bid & 7;
  const int within = bid >> 3;
  const int bh = xcd * 4 + (within & 3);
  const int c = 31 - (within >> 2);

  const bf16* Qb = Qh + (size_t)bh * S_LEN * HD;
  const bf16* Kb = Kh + (size_t)bh * S_LEN * HD;
  const bf16* Vb = Vt + (size_t)bh * HD * S_LEN;

  int stK[2], stV[2], stL[2];
#pragma unroll
  for (int i = 0; i < 2; ++i) {
    const int lin = i * 256 + tid;
    const int row = lin >> 3;
    const int colb = (lin & 7) * 16;
    const int scol = colb ^ ((row & 7) << 4);
    stK[i] = row * HD + (scol >> 1);
    stV[i] = row * S_LEN + (scol >> 1);
    stL[i] = lin * 8;
  }
  const int swz = (q31 & 7) << 4;

#define STAGE(t, buf)                                                          \
  {                                                                            \
    const bf16* kb_ = Kb + (size_t)(t) * 64 * HD;                              \
    const bf16* vb_ = Vb + (t) * 64;                                           \
    _Pragma("unroll") for (int i = 0; i < 2; ++i) {                            \
      gload_lds16(kb_ + stK[i], &Kl[buf][stL[i]]);                             \
      gload_lds16(vb_ + stV[i], &Vl[buf][stL[i]]);                             \
    }                                                                          \
  }

  {
    const int q0 = c << 6;
    const int nt = c + 1;
    const int q0w = q0 + (qh << 5);
    const int qg = q0w + q31;
    const int nt_w = (w == 1) ? nt - 1 : nt;
    const bool maskw = (w == 0) || (w == 3);

    bf16x8 qf[4];
#pragma unroll
    for (int ks = 0; ks < 4; ++ks)
      qf[ks] = *(const bf16x8*)&Qb[(size_t)qg * HD + ks * 16 + 8 * h];

    f32x16 acc0 = {}, acc1 = {};
    float m = -1e30f, l = 0.f;

    STAGE(0, 0)
    if (nt > 1) STAGE(1, 1)

    int cur = 0;
    for (int kt = 0; kt < nt; ++kt) {
      if (kt + 1 < nt) asm volatile("s_waitcnt vmcnt(4)" ::: "memory");
      else             asm volatile("s_waitcnt vmcnt(0)" ::: "memory");
      __builtin_amdgcn_s_barrier();

      if (kt + 2 < nt) {
        int nxt = cur + 2; if (nxt >= 3) nxt -= 3;
        STAGE(kt + 2, nxt)
      }

      if (kt < nt_w) {
        const bf16* KlC = &Kl[cur][0];
        const bf16* VlC = &Vl[cur][0];

        bf16x8 kf[4];
#pragma unroll
        for (int ks = 0; ks < 4; ++ks) {
          const int cc = (32 * ks + 16 * h) ^ swz;
          kf[ks] = *(const bf16x8*)((const char*)KlC + (koff + q31) * 128 + cc);
        }

        f32x16 p0 = {};
        __builtin_amdgcn_s_setprio(1);
#pragma unroll
        for (int ks = 0; ks < 4; ++ks)
          p0 = __builtin_amdgcn_mfma_f32_32x32x16_bf16(kf[ks], qf[ks], p0, 0, 0, 0);
        __builtin_amdgcn_s_setprio(0);

        bf16x8 vf[4];
#pragma unroll
        for (int ks = 0; ks < 2; ++ks)
#pragma unroll
          for (int db = 0; db < 2; ++db) {
            const int cc = (64 * kh + 32 * ks + 16 * h) ^ swz;
            vf[ks * 2 + db] =
                *(const bf16x8*)((const char*)VlC + (db * 32 + q31) * 128 + cc);
          }

        if (maskw && kt == nt - 1) {
#pragma unroll
          for (int r = 0; r < 16; ++r) {
            const int key = (kt << 6) + koff + (r & 3) + 8 * (r >> 2) + 4 * h;
            if (key > qg) p0[r] = -1e30f;
          }
        }
        float t_[16];
#pragma unroll
        for (int r = 0; r < 16; ++r) t_[r] = p0[r];
#pragma unroll
        for (int s = 8; s >= 1; s >>= 1)
#pragma unroll
          for (int r = 0; r < s; ++r) t_[r] = fmaxf(t_[r], t_[r + s]);
        const float pmax = fmaxf(t_[0], __shfl_xor(t_[0], 32));
        if (!__all(pmax - m <= 8.0f)) {
          const float mn = fmaxf(m, pmax);
          const float al = exp2f(m - mn);
          m = mn;
          l *= al;
#pragma unroll
          for (int r = 0; r < 16; ++r) { acc0[r] *= al; acc1[r] *= al; }
        }
        float sv[16];
#pragma unroll
        for (int r = 0; r < 16; ++r) {
          p0[r] = exp2f(p0[r] - m);
          sv[r] = p0[r];
        }
#pragma unroll
        for (int s = 8; s >= 1; s >>= 1)
#pragma unroll
          for (int r = 0; r < s; ++r) sv[r] += sv[r + s];
        l += sv[0] + __shfl_xor(sv[0], 32);

        unsigned wv[8];
#pragma unroll
        for (int mm = 0; mm < 8; ++mm)
          wv[mm] = packbf(p0[2 * mm], p0[2 * mm + 1]);
        pl32swap(wv[0], wv[2]);
        pl32swap(wv[1], wv[3]);
        pl32swap(wv[4], wv[6]);
        pl32swap(wv[5], wv[7]);

        __builtin_amdgcn_s_setprio(1);
        {
          u32x4 pu0 = {wv[0], wv[1], wv[2], wv[3]};
          const bf16x8 pf0 = __builtin_bit_cast(bf16x8, pu0);
          acc0 = __builtin_amdgcn_mfma_f32_32x32x16_bf16(vf[0], pf0, acc0, 0, 0, 0);
          acc1 = __builtin_amdgcn_mfma_f32_32x32x16_bf16(vf[1], pf0, acc1, 0, 0, 0);
          u32x4 pu1 = {wv[4], wv[5], wv[6], wv[7]};
          const bf16x8 pf1 = __builtin_bit_cast(bf16x8, pu1);
          acc0 = __builtin_amdgcn_mfma_f32_32x32x16_bf16(vf[2], pf1, acc0, 0, 0, 0);
          acc1 = __builtin_amdgcn_mfma_f32_32x32x16_bf16(vf[3], pf1, acc1, 0, 0, 0);
        }
        __builtin_amdgcn_s_setprio(0);
      }

      ++cur; if (cur == 3) cur = 0;
    }

    // ---- split-K combine across key-half waves (scratch = Kl area) ----
    float* scr = (float*)&Kl[0][0];
    float* s = scr + (size_t)qh * (64 * 34) + lane * 34;
    __syncthreads();
    if (kh) {
#pragma unroll
      for (int r = 0; r < 16; ++r) { s[r] = acc0[r]; s[16 + r] = acc1[r]; }
      s[32] = m;
      s[33] = l;
    }
    __syncthreads();
    if (!kh) {
      const float m1 = s[32], l1 = s[33];
      const float mn = fmaxf(m, m1);
      const float a0 = exp2f(m - mn), a1 = exp2f(m1 - mn);
      const float linv = 1.0f / (a0 * l + a1 * l1);
      const int b = bh >> 4, hh = bh & 15;
      bf16* orow = AO + ((size_t)(b * S_LEN + qg)) * DM + hh * HD;
#pragma unroll
      for (int mm = 0; mm < 4; ++mm) {
        bf16x4 ov0, ov1;
#pragma unroll
        for (int t2 = 0; t2 < 4; ++t2) {
          ov0[t2] = (bf16)((a0 * acc0[4 * mm + t2] + a1 * s[4 * mm + t2]) * linv);
          ov1[t2] = (bf16)((a0 * acc1[4 * mm + t2] + a1 * s[16 + 4 * mm + t2]) * linv);
        }
        *(bf16x4*)&orow[8 * mm + 4 * h] = ov0;
        *(bf16x4*)&orow[32 + 8 * mm + 4 * h] = ov1;
      }
    }
  }
#undef STAGE
}

// ---------------- launch ----------------
extern "C" void kernel_launch(void* const* d_in, const int* in_sizes, int n_in,
                              void* d_out, int out_size, void* d_ws, size_t ws_size,
                              hipStream_t stream) {
  const float* q  = (const float*)d_in[0];
  const float* k  = (const float*)d_in[1];
  const float* v  = (const float*)d_in[2];
  const float* Wq = (const float*)d_in[3];
  const float* bq = (const float*)d_in[4];
  const float* Wk = (const float*)d_in[5];
  const float* bk = (const float*)d_in[6];
  const float* Wv = (const float*)d_in[7];
  const float* bv = (const float*)d_in[8];
  const float* Wo = (const float*)d_in[9];
  const float* bo = (const float*)d_in[10];

  const int NTOK = 2 * S_LEN;          // 4096

  bf16* qb  = (bf16*)d_ws;             // q,k,v bf16: 3 * NQKV (consecutive)
  bf16* Wqb = qb + 3 * (size_t)NQKV;   // Wq,Wk,Wv,Wo bf16: 4 * NW (consecutive)
  bf16* Wob = Wqb + 3 * (size_t)NW;
  bf16* Qh  = Wqb + 4 * (size_t)NW;    // Qh,Kh,Vt bf16: 3 * NQKV (consecutive)
  bf16* Kh  = Qh + (size_t)NQKV;
  bf16* Vt  = Kh + (size_t)NQKV;
  bf16* AO  = Vt + (size_t)NQKV;

  const int cvt_blocks = (3 * NQKV + 4 * NW) / 8 / 256;
  cvt_all<<<cvt_blocks, 256, 0, stream>>>(q, k, v, Wq, Wk, Wv, Wo, qb);

  // fused QKV projection: M=4096, N=3072, K=1024
  gemm_bt<3><<<dim3(3 * DM / 128, NTOK / 128), 256, 0, stream>>>(
      qb, Wqb, bq, bk, bv, Qh, NTOK, 3 * DM, DM, QK_SCALE);

  // attention: 1024 single-chunk blocks x 256 threads, heavy-first, 3/CU
  attn_fwd13<<<dim3(1024), 256, 0, stream>>>(Qh, Kh, Vt, AO);

  // output projection -> fp32 d_out
  gemm_bt<2><<<dim3(DM / 128, NTOK / 128), 256, 0, stream>>>(
      AO, Wob, bo, bo, bo, d_out, NTOK, DM, DM, 1.0f);
}

// Round 20
// 110.278 us; speedup vs baseline: 1.6837x; 1.0163x over previous
//
#include <hip/hip_runtime.h>
#include <hip/hip_bf16.h>
#include <cstdint>
#include <cstddef>

typedef __bf16 bf16;
typedef __bf16 bf16x2 __attribute__((ext_vector_type(2)));
typedef __bf16 bf16x4 __attribute__((ext_vector_type(4)));
typedef __bf16 bf16x8 __attribute__((ext_vector_type(8)));
typedef float f32x4 __attribute__((ext_vector_type(4)));
typedef float f32x16 __attribute__((ext_vector_type(16)));
typedef unsigned int u32x4 __attribute__((ext_vector_type(4)));

#define S_LEN 2048
#define DM 1024
#define NH 16
#define HD 64
#define NQKV (4096 * 1024)   // tokens * DM
#define NW (1024 * 1024)
// (1/sqrt(64)) * log2(e): fold softmax scale + exp2 conversion into Q
#define QK_SCALE 0.18033688011112042f

__device__ __forceinline__ void gload_lds16(const bf16* g, bf16* l) {
  __builtin_amdgcn_global_load_lds(
      (const __attribute__((address_space(1))) void*)g,
      (__attribute__((address_space(3))) void*)l, 16, 0, 0);
}

__device__ __forceinline__ unsigned packbf(float lo, float hi) {
  bf16x2 t;
  t[0] = (bf16)lo;
  t[1] = (bf16)hi;
  return __builtin_bit_cast(unsigned, t);
}

// v_permlane32_swap_b32: new_a[l>=32] = b_old[l-32]; new_b[l<32] = a_old[l+32]
__device__ __forceinline__ void pl32swap(unsigned& a, unsigned& b) {
#if __has_builtin(__builtin_amdgcn_permlane32_swap)
  auto r = __builtin_amdgcn_permlane32_swap((int)a, (int)b, false, false);
  a = (unsigned)r[0];
  b = (unsigned)r[1];
#else
  asm volatile("v_permlane32_swap_b32 %0, %1" : "+v"(a), "+v"(b));
#endif
}

// ---------------- fused fp32 -> bf16 convert for all 7 tensors ----------------
__global__ __launch_bounds__(256) void cvt_all(
    const float* __restrict__ q, const float* __restrict__ k, const float* __restrict__ v,
    const float* __restrict__ Wq, const float* __restrict__ Wk, const float* __restrict__ Wv,
    const float* __restrict__ Wo, bf16* __restrict__ out) {
  const size_t i = ((size_t)blockIdx.x * 256 + threadIdx.x) * 8;
  const float* src;
  size_t off;
  if (i < (size_t)NQKV) { src = q; off = i; }
  else if (i < 2ull * NQKV) { src = k; off = i - NQKV; }
  else if (i < 3ull * NQKV) { src = v; off = i - 2ull * NQKV; }
  else {
    const size_t j = i - 3ull * NQKV;
    if (j < (size_t)NW) { src = Wq; off = j; }
    else if (j < 2ull * NW) { src = Wk; off = j - NW; }
    else if (j < 3ull * NW) { src = Wv; off = j - 2ull * NW; }
    else { src = Wo; off = j - 3ull * NW; }
  }
  const float4 a = *(const float4*)(src + off);
  const float4 b = *(const float4*)(src + off + 4);
  bf16x8 o;
  o[0] = (bf16)a.x; o[1] = (bf16)a.y; o[2] = (bf16)a.z; o[3] = (bf16)a.w;
  o[4] = (bf16)b.x; o[5] = (bf16)b.y; o[6] = (bf16)b.z; o[7] = (bf16)b.w;
  *(bf16x8*)(out + i) = o;
}

// ---------------- GEMM: Y[m,n] = sum_k A[m,k] * W[n,k] + bias[n] ----------------
// BK=32, 3-slot ring + counted vmcnt(4) + raw barrier (r13 attn ledger):
//   iter t: vmcnt(4) [stage(t) landed; stage(t+1) in flight] ; s_barrier ;
//           stage(t+2) -> slot (t+2)%3 [readers (iter t-1) retired pre-barrier];
//           compute(t) from slot t%3.  No trailing barrier, no full drain.
// 48KB LDS -> 3 blocks/CU, full 768-block grid co-resident.
// MODE 2: out fp32, row-major [M,N]   (final projection)
// MODE 3: fused QKV; seg = n0>>10: seg0 Q head-major*QK_SCALE, seg1 K head-major,
//         seg2 V per-head transposed [B,H,hd,S] via LDS-transposed epilogue.
template <int MODE>
__global__ __launch_bounds__(256, 3) void gemm_bt(
    const bf16* __restrict__ A, const bf16* __restrict__ W,
    const float* __restrict__ bias0, const float* __restrict__ bias1,
    const float* __restrict__ bias2, void* __restrict__ Out,
    int M, int N, int K, float scale) {
  __shared__ __align__(16) bf16 sm[3 * 2 * 128 * 32];  // 3 slots x (A 8KB + B 8KB)
  const int tid = threadIdx.x;
  const int lane = tid & 63, w = tid >> 6;
  const int wr = w >> 1, wc = w & 1;
  const int r16 = lane & 15, grp = lane >> 4;

  // XCD swizzle: consecutive blocks within an XCD share A-panels
  int flat = blockIdx.y * gridDim.x + blockIdx.x;
  const int cpx = (gridDim.x * gridDim.y) >> 3;
  flat = (flat & 7) * cpx + (flat >> 3);
  const int m0 = (flat / gridDim.x) * 128;
  const int n0 = (flat % gridDim.x) * 128;

  const int seg = n0 >> 10;
  const bf16* Ab = (MODE == 3) ? A + (size_t)seg * NQKV : A;

  f32x4 acc[4][4] = {};

  // staging offsets: per thread 2 A-loads + 2 B-loads of 16B (128x32 tile)
  int stG[2], stL[2];
#pragma unroll
  for (int j = 0; j < 2; ++j) {
    const int lin = j * 256 + tid;             // 0..511
    stG[j] = (lin >> 2) * K + (lin & 3) * 8;   // row 0..127, k-off 0..24
    stL[j] = lin * 8;
  }

#define GSTAGE(t, s)                                                           \
  {                                                                            \
    const int k0_ = (t) << 5;                                                  \
    bf16* as_ = sm + (s) * 8192;                                               \
    bf16* bs_ = as_ + 4096;                                                    \
    _Pragma("unroll") for (int j = 0; j < 2; ++j) {                            \
      gload_lds16(&Ab[(size_t)m0 * K + k0_ + stG[j]], &as_[stL[j]]);           \
      gload_lds16(&W[(size_t)n0 * K + k0_ + stG[j]], &bs_[stL[j]]);            \
    }                                                                          \
  }

  const int nk = K >> 5;   // 32
  GSTAGE(0, 0)
  GSTAGE(1, 1)             // K >= 64 always here

  int cur = 0;
  for (int t = 0; t < nk; ++t) {
    // stage(t) landed when only stage(t+1)'s 4 loads remain outstanding
    if (t + 1 < nk) asm volatile("s_waitcnt vmcnt(4)" ::: "memory");
    else            asm volatile("s_waitcnt vmcnt(0)" ::: "memory");
    __builtin_amdgcn_s_barrier();

    if (t + 2 < nk) {
      int nxt = cur + 2; if (nxt >= 3) nxt -= 3;
      GSTAGE(t + 2, nxt)
    }

    const bf16* Asl = sm + cur * 8192;
    const bf16* Bsl = Asl + 4096;
    {
      bf16x8 af[4], bfr[4];
#pragma unroll
      for (int m = 0; m < 4; ++m)
        af[m] = *(const bf16x8*)&Asl[(wr * 64 + m * 16 + r16) * 32 + grp * 8];
#pragma unroll
      for (int n = 0; n < 4; ++n)
        bfr[n] = *(const bf16x8*)&Bsl[(wc * 64 + n * 16 + r16) * 32 + grp * 8];
#pragma unroll
      for (int m = 0; m < 4; ++m)
#pragma unroll
        for (int n = 0; n < 4; ++n)
          acc[m][n] = __builtin_amdgcn_mfma_f32_16x16x32_bf16(af[m], bfr[n], acc[m][n], 0, 0, 0);
    }
    ++cur; if (cur == 3) cur = 0;
  }
#undef GSTAGE

  const float* bp = (MODE == 3) ? (seg == 0 ? bias0 : (seg == 1 ? bias1 : bias2)) : bias0;
  const float sc = (MODE == 3) ? (seg == 0 ? scale : 1.0f) : scale;

  if (MODE == 3 && seg == 2) {
    // ---- V^T epilogue: transpose each wave's 64x64 quadrant via LDS ----
    __syncthreads();  // all slots' ds_reads retired before reusing sm as T
    bf16* T = sm + w * (32 * 76);
    const int b = (m0 + wr * 64) >> 11;
    const int srow0 = (m0 + wr * 64) & 2047;
    bf16* base2 = (bf16*)Out + 2 * (size_t)NQKV;
#pragma unroll
    for (int p = 0; p < 2; ++p) {
#pragma unroll
      for (int nn = 0; nn < 2; ++nn) {
        const int n = 2 * p + nn;
#pragma unroll
        for (int mq = 0; mq < 4; ++mq)
#pragma unroll
          for (int r = 0; r < 4; ++r) {
            const int d_l = nn * 16 + r16;
            const int s_l = mq * 16 + grp * 4 + r;
            const int cs = (n0 + wc * 64 + n * 16 + r16) & 1023;
            T[d_l * 76 + s_l] = (bf16)(acc[mq][n][r] + bp[cs]);
          }
      }
      __syncthreads();
#pragma unroll
      for (int j = 0; j < 4; ++j) {
        const int d_l = j * 8 + (lane >> 3);
        const int scnk = lane & 7;
        const uint2 lo = *(const uint2*)&T[d_l * 76 + scnk * 8];
        const uint2 hi = *(const uint2*)&T[d_l * 76 + scnk * 8 + 4];
        const int cs = (n0 + wc * 64 + p * 32 + d_l) & 1023;
        const int hh = cs >> 6, dd = cs & 63;
        bf16* dst = base2 + ((size_t)(b * NH + hh) * HD + dd) * S_LEN + srow0 + scnk * 8;
        uint4 val; val.x = lo.x; val.y = lo.y; val.z = hi.x; val.w = hi.y;
        *(uint4*)dst = val;
      }
      __syncthreads();
    }
    return;
  }

#pragma unroll
  for (int m = 0; m < 4; ++m) {
#pragma unroll
    for (int n = 0; n < 4; ++n) {
#pragma unroll
      for (int r = 0; r < 4; ++r) {
        const int row = m0 + wr * 64 + m * 16 + grp * 4 + r;
        const int col = n0 + wc * 64 + n * 16 + r16;
        const int cs = col & 1023;
        const float v = (acc[m][n][r] + bp[cs]) * sc;
        if (MODE == 3) {  // seg 0/1: head-major
          const int b = row >> 11, s = row & 2047, h = cs >> 6, d = cs & 63;
          bf16* base = (bf16*)Out + (size_t)seg * NQKV;
          base[((size_t)(b * NH + h) * S_LEN + s) * HD + d] = (bf16)v;
        } else {
          ((float*)Out)[(size_t)row * N + col] = v;
        }
      }
    }
  }
}

// ---------------- causal flash attention: single-chunk blocks, 3/CU ------------
// (round-13 structure, session best: 45.0us, Occ 25.4%)
__global__ __launch_bounds__(256, 3) void attn_fwd13(
    const bf16* __restrict__ Qh, const bf16* __restrict__ Kh,
    const bf16* __restrict__ Vt, bf16* __restrict__ AO) {
  __shared__ __align__(16) bf16 Kl[3][64 * 64];
  __shared__ __align__(16) bf16 Vl[3][64 * 64];

  const int tid = threadIdx.x;
  const int lane = tid & 63, w = tid >> 6;
  const int q31 = lane & 31, h = lane >> 5;
  const int qh = w >> 1, kh = w & 1;
  const int koff = kh << 5;

  const int bid = blockIdx.x;
  const int xcd = bid & 7;
  const int within = bid >> 3;
  const int bh = xcd * 4 + (within & 3);
  const int c = 31 - (within >> 2);

  const bf16* Qb = Qh + (size_t)bh * S_LEN * HD;
  const bf16* Kb = Kh + (size_t)bh * S_LEN * HD;
  const bf16* Vb = Vt + (size_t)bh * HD * S_LEN;

  int stK[2], stV[2], stL[2];
#pragma unroll
  for (int i = 0; i < 2; ++i) {
    const int lin = i * 256 + tid;
    const int row = lin >> 3;
    const int colb = (lin & 7) * 16;
    const int scol = colb ^ ((row & 7) << 4);
    stK[i] = row * HD + (scol >> 1);
    stV[i] = row * S_LEN + (scol >> 1);
    stL[i] = lin * 8;
  }
  const int swz = (q31 & 7) << 4;

#define STAGE(t, buf)                                                          \
  {                                                                            \
    const bf16* kb_ = Kb + (size_t)(t) * 64 * HD;                              \
    const bf16* vb_ = Vb + (t) * 64;                                           \
    _Pragma("unroll") for (int i = 0; i < 2; ++i) {                            \
      gload_lds16(kb_ + stK[i], &Kl[buf][stL[i]]);                             \
      gload_lds16(vb_ + stV[i], &Vl[buf][stL[i]]);                             \
    }                                                                          \
  }

  {
    const int q0 = c << 6;
    const int nt = c + 1;
    const int q0w = q0 + (qh << 5);
    const int qg = q0w + q31;
    const int nt_w = (w == 1) ? nt - 1 : nt;
    const bool maskw = (w == 0) || (w == 3);

    bf16x8 qf[4];
#pragma unroll
    for (int ks = 0; ks < 4; ++ks)
      qf[ks] = *(const bf16x8*)&Qb[(size_t)qg * HD + ks * 16 + 8 * h];

    f32x16 acc0 = {}, acc1 = {};
    float m = -1e30f, l = 0.f;

    STAGE(0, 0)
    if (nt > 1) STAGE(1, 1)

    int cur = 0;
    for (int kt = 0; kt < nt; ++kt) {
      if (kt + 1 < nt) asm volatile("s_waitcnt vmcnt(4)" ::: "memory");
      else             asm volatile("s_waitcnt vmcnt(0)" ::: "memory");
      __builtin_amdgcn_s_barrier();

      if (kt + 2 < nt) {
        int nxt = cur + 2; if (nxt >= 3) nxt -= 3;
        STAGE(kt + 2, nxt)
      }

      if (kt < nt_w) {
        const bf16* KlC = &Kl[cur][0];
        const bf16* VlC = &Vl[cur][0];

        bf16x8 kf[4];
#pragma unroll
        for (int ks = 0; ks < 4; ++ks) {
          const int cc = (32 * ks + 16 * h) ^ swz;
          kf[ks] = *(const bf16x8*)((const char*)KlC + (koff + q31) * 128 + cc);
        }

        f32x16 p0 = {};
        __builtin_amdgcn_s_setprio(1);
#pragma unroll
        for (int ks = 0; ks < 4; ++ks)
          p0 = __builtin_amdgcn_mfma_f32_32x32x16_bf16(kf[ks], qf[ks], p0, 0, 0, 0);
        __builtin_amdgcn_s_setprio(0);

        bf16x8 vf[4];
#pragma unroll
        for (int ks = 0; ks < 2; ++ks)
#pragma unroll
          for (int db = 0; db < 2; ++db) {
            const int cc = (64 * kh + 32 * ks + 16 * h) ^ swz;
            vf[ks * 2 + db] =
                *(const bf16x8*)((const char*)VlC + (db * 32 + q31) * 128 + cc);
          }

        if (maskw && kt == nt - 1) {
#pragma unroll
          for (int r = 0; r < 16; ++r) {
            const int key = (kt << 6) + koff + (r & 3) + 8 * (r >> 2) + 4 * h;
            if (key > qg) p0[r] = -1e30f;
          }
        }
        float t_[16];
#pragma unroll
        for (int r = 0; r < 16; ++r) t_[r] = p0[r];
#pragma unroll
        for (int s = 8; s >= 1; s >>= 1)
#pragma unroll
          for (int r = 0; r < s; ++r) t_[r] = fmaxf(t_[r], t_[r + s]);
        const float pmax = fmaxf(t_[0], __shfl_xor(t_[0], 32));
        if (!__all(pmax - m <= 8.0f)) {
          const float mn = fmaxf(m, pmax);
          const float al = exp2f(m - mn);
          m = mn;
          l *= al;
#pragma unroll
          for (int r = 0; r < 16; ++r) { acc0[r] *= al; acc1[r] *= al; }
        }
        float sv[16];
#pragma unroll
        for (int r = 0; r < 16; ++r) {
          p0[r] = exp2f(p0[r] - m);
          sv[r] = p0[r];
        }
#pragma unroll
        for (int s = 8; s >= 1; s >>= 1)
#pragma unroll
          for (int r = 0; r < s; ++r) sv[r] += sv[r + s];
        l += sv[0] + __shfl_xor(sv[0], 32);

        unsigned wv[8];
#pragma unroll
        for (int mm = 0; mm < 8; ++mm)
          wv[mm] = packbf(p0[2 * mm], p0[2 * mm + 1]);
        pl32swap(wv[0], wv[2]);
        pl32swap(wv[1], wv[3]);
        pl32swap(wv[4], wv[6]);
        pl32swap(wv[5], wv[7]);

        __builtin_amdgcn_s_setprio(1);
        {
          u32x4 pu0 = {wv[0], wv[1], wv[2], wv[3]};
          const bf16x8 pf0 = __builtin_bit_cast(bf16x8, pu0);
          acc0 = __builtin_amdgcn_mfma_f32_32x32x16_bf16(vf[0], pf0, acc0, 0, 0, 0);
          acc1 = __builtin_amdgcn_mfma_f32_32x32x16_bf16(vf[1], pf0, acc1, 0, 0, 0);
          u32x4 pu1 = {wv[4], wv[5], wv[6], wv[7]};
          const bf16x8 pf1 = __builtin_bit_cast(bf16x8, pu1);
          acc0 = __builtin_amdgcn_mfma_f32_32x32x16_bf16(vf[2], pf1, acc0, 0, 0, 0);
          acc1 = __builtin_amdgcn_mfma_f32_32x32x16_bf16(vf[3], pf1, acc1, 0, 0, 0);
        }
        __builtin_amdgcn_s_setprio(0);
      }

      ++cur; if (cur == 3) cur = 0;
    }

    // ---- split-K combine across key-half waves (scratch = Kl area) ----
    float* scr = (float*)&Kl[0][0];
    float* s = scr + (size_t)qh * (64 * 34) + lane * 34;
    __syncthreads();
    if (kh) {
#pragma unroll
      for (int r = 0; r < 16; ++r) { s[r] = acc0[r]; s[16 + r] = acc1[r]; }
      s[32] = m;
      s[33] = l;
    }
    __syncthreads();
    if (!kh) {
      const float m1 = s[32], l1 = s[33];
      const float mn = fmaxf(m, m1);
      const float a0 = exp2f(m - mn), a1 = exp2f(m1 - mn);
      const float linv = 1.0f / (a0 * l + a1 * l1);
      const int b = bh >> 4, hh = bh & 15;
      bf16* orow = AO + ((size_t)(b * S_LEN + qg)) * DM + hh * HD;
#pragma unroll
      for (int mm = 0; mm < 4; ++mm) {
        bf16x4 ov0, ov1;
#pragma unroll
        for (int t2 = 0; t2 < 4; ++t2) {
          ov0[t2] = (bf16)((a0 * acc0[4 * mm + t2] + a1 * s[4 * mm + t2]) * linv);
          ov1[t2] = (bf16)((a0 * acc1[4 * mm + t2] + a1 * s[16 + 4 * mm + t2]) * linv);
        }
        *(bf16x4*)&orow[8 * mm + 4 * h] = ov0;
        *(bf16x4*)&orow[32 + 8 * mm + 4 * h] = ov1;
      }
    }
  }
#undef STAGE
}

// ---------------- launch ----------------
extern "C" void kernel_launch(void* const* d_in, const int* in_sizes, int n_in,
                              void* d_out, int out_size, void* d_ws, size_t ws_size,
                              hipStream_t stream) {
  const float* q  = (const float*)d_in[0];
  const float* k  = (const float*)d_in[1];
  const float* v  = (const float*)d_in[2];
  const float* Wq = (const float*)d_in[3];
  const float* bq = (const float*)d_in[4];
  const float* Wk = (const float*)d_in[5];
  const float* bk = (const float*)d_in[6];
  const float* Wv = (const float*)d_in[7];
  const float* bv = (const float*)d_in[8];
  const float* Wo = (const float*)d_in[9];
  const float* bo = (const float*)d_in[10];

  const int NTOK = 2 * S_LEN;          // 4096

  bf16* qb  = (bf16*)d_ws;             // q,k,v bf16: 3 * NQKV (consecutive)
  bf16* Wqb = qb + 3 * (size_t)NQKV;   // Wq,Wk,Wv,Wo bf16: 4 * NW (consecutive)
  bf16* Wob = Wqb + 3 * (size_t)NW;
  bf16* Qh  = Wqb + 4 * (size_t)NW;    // Qh,Kh,Vt bf16: 3 * NQKV (consecutive)
  bf16* Kh  = Qh + (size_t)NQKV;
  bf16* Vt  = Kh + (size_t)NQKV;
  bf16* AO  = Vt + (size_t)NQKV;

  const int cvt_blocks = (3 * NQKV + 4 * NW) / 8 / 256;
  cvt_all<<<cvt_blocks, 256, 0, stream>>>(q, k, v, Wq, Wk, Wv, Wo, qb);

  // fused QKV projection: M=4096, N=3072, K=1024
  gemm_bt<3><<<dim3(3 * DM / 128, NTOK / 128), 256, 0, stream>>>(
      qb, Wqb, bq, bk, bv, Qh, NTOK, 3 * DM, DM, QK_SCALE);

  // attention: 1024 single-chunk blocks x 256 threads, heavy-first, 3/CU
  attn_fwd13<<<dim3(1024), 256, 0, stream>>>(Qh, Kh, Vt, AO);

  // output projection -> fp32 d_out
  gemm_bt<2><<<dim3(DM / 128, NTOK / 128), 256, 0, stream>>>(
      AO, Wob, bo, bo, bo, d_out, NTOK, DM, DM, 1.0f);
}

// Round 21
// 110.089 us; speedup vs baseline: 1.6866x; 1.0017x over previous
//
#include <hip/hip_runtime.h>
#include <hip/hip_bf16.h>
#include <cstdint>
#include <cstddef>

typedef __bf16 bf16;
typedef __bf16 bf16x2 __attribute__((ext_vector_type(2)));
typedef __bf16 bf16x4 __attribute__((ext_vector_type(4)));
typedef __bf16 bf16x8 __attribute__((ext_vector_type(8)));
typedef float f32x4 __attribute__((ext_vector_type(4)));
typedef float f32x16 __attribute__((ext_vector_type(16)));
typedef unsigned int u32x4 __attribute__((ext_vector_type(4)));

#define S_LEN 2048
#define DM 1024
#define NH 16
#define HD 64
#define NQKV (4096 * 1024)   // tokens * DM
#define NW (1024 * 1024)
// (1/sqrt(64)) * log2(e): fold softmax scale + exp2 conversion into Q
#define QK_SCALE 0.18033688011112042f

__device__ __forceinline__ void gload_lds16(const bf16* g, bf16* l) {
  __builtin_amdgcn_global_load_lds(
      (const __attribute__((address_space(1))) void*)g,
      (__attribute__((address_space(3))) void*)l, 16, 0, 0);
}

__device__ __forceinline__ unsigned packbf(float lo, float hi) {
  bf16x2 t;
  t[0] = (bf16)lo;
  t[1] = (bf16)hi;
  return __builtin_bit_cast(unsigned, t);
}

// v_permlane32_swap_b32: new_a[l>=32] = b_old[l-32]; new_b[l<32] = a_old[l+32]
__device__ __forceinline__ void pl32swap(unsigned& a, unsigned& b) {
#if __has_builtin(__builtin_amdgcn_permlane32_swap)
  auto r = __builtin_amdgcn_permlane32_swap((int)a, (int)b, false, false);
  a = (unsigned)r[0];
  b = (unsigned)r[1];
#else
  asm volatile("v_permlane32_swap_b32 %0, %1" : "+v"(a), "+v"(b));
#endif
}

// ---------------- fused fp32 -> bf16 convert for all 7 tensors ----------------
__global__ __launch_bounds__(256) void cvt_all(
    const float* __restrict__ q, const float* __restrict__ k, const float* __restrict__ v,
    const float* __restrict__ Wq, const float* __restrict__ Wk, const float* __restrict__ Wv,
    const float* __restrict__ Wo, bf16* __restrict__ out) {
  const size_t i = ((size_t)blockIdx.x * 256 + threadIdx.x) * 8;
  const float* src;
  size_t off;
  if (i < (size_t)NQKV) { src = q; off = i; }
  else if (i < 2ull * NQKV) { src = k; off = i - NQKV; }
  else if (i < 3ull * NQKV) { src = v; off = i - 2ull * NQKV; }
  else {
    const size_t j = i - 3ull * NQKV;
    if (j < (size_t)NW) { src = Wq; off = j; }
    else if (j < 2ull * NW) { src = Wk; off = j - NW; }
    else if (j < 3ull * NW) { src = Wv; off = j - 2ull * NW; }
    else { src = Wo; off = j - 3ull * NW; }
  }
  const float4 a = *(const float4*)(src + off);
  const float4 b = *(const float4*)(src + off + 4);
  bf16x8 o;
  o[0] = (bf16)a.x; o[1] = (bf16)a.y; o[2] = (bf16)a.z; o[3] = (bf16)a.w;
  o[4] = (bf16)b.x; o[5] = (bf16)b.y; o[6] = (bf16)b.z; o[7] = (bf16)b.w;
  *(bf16x8*)(out + i) = o;
}

// ---------------- GEMM: Y[m,n] = sum_k A[m,k] * W[n,k] + bias[n] ----------------
// BK=32, 3-slot ring + counted vmcnt(4) + raw barrier (r20 proven) + T2 swizzle:
// LDS stays LINEAR (gload_lds); the global SOURCE k-chunk is permuted
// chunk' = chunk ^ (row&3) and the frag read XORs the same pattern
// ((grp*16) ^ ((row&3)<<4)) -- involution both sides (rule #21). Rows
// {0,4,8,12}... share chunk positions -> 8-way bank conflict drops to ~4-way.
// MODE 2: out fp32, row-major [M,N]   (final projection)
// MODE 3: fused QKV; seg = n0>>10: seg0 Q head-major*QK_SCALE, seg1 K head-major,
//         seg2 V per-head transposed [B,H,hd,S] via LDS-transposed epilogue.
template <int MODE>
__global__ __launch_bounds__(256, 3) void gemm_bt(
    const bf16* __restrict__ A, const bf16* __restrict__ W,
    const float* __restrict__ bias0, const float* __restrict__ bias1,
    const float* __restrict__ bias2, void* __restrict__ Out,
    int M, int N, int K, float scale) {
  __shared__ __align__(16) bf16 sm[3 * 2 * 128 * 32];  // 3 slots x (A 8KB + B 8KB)
  const int tid = threadIdx.x;
  const int lane = tid & 63, w = tid >> 6;
  const int wr = w >> 1, wc = w & 1;
  const int r16 = lane & 15, grp = lane >> 4;

  // XCD swizzle: consecutive blocks within an XCD share A-panels
  int flat = blockIdx.y * gridDim.x + blockIdx.x;
  const int cpx = (gridDim.x * gridDim.y) >> 3;
  flat = (flat & 7) * cpx + (flat >> 3);
  const int m0 = (flat / gridDim.x) * 128;
  const int n0 = (flat % gridDim.x) * 128;

  const int seg = n0 >> 10;
  const bf16* Ab = (MODE == 3) ? A + (size_t)seg * NQKV : A;

  f32x4 acc[4][4] = {};

  // staging offsets: per thread 2 A-loads + 2 B-loads of 16B (128x32 tile).
  // Source k-chunk pre-swizzled: chunk' = (lin&3) ^ (row&3) (16B chunks).
  int stG[2], stL[2];
#pragma unroll
  for (int j = 0; j < 2; ++j) {
    const int lin = j * 256 + tid;             // 0..511
    const int row = lin >> 2;                  // 0..127
    const int ch = (lin & 3) ^ (row & 3);      // swizzled source chunk
    stG[j] = row * K + ch * 8;
    stL[j] = lin * 8;                          // LDS linear
  }

#define GSTAGE(t, s)                                                           \
  {                                                                            \
    const int k0_ = (t) << 5;                                                  \
    bf16* as_ = sm + (s) * 8192;                                               \
    bf16* bs_ = as_ + 4096;                                                    \
    _Pragma("unroll") for (int j = 0; j < 2; ++j) {                            \
      gload_lds16(&Ab[(size_t)m0 * K + k0_ + stG[j]], &as_[stL[j]]);           \
      gload_lds16(&W[(size_t)n0 * K + k0_ + stG[j]], &bs_[stL[j]]);            \
    }                                                                          \
  }

  const int nk = K >> 5;   // 32
  GSTAGE(0, 0)
  GSTAGE(1, 1)             // K >= 64 always here

  int cur = 0;
  for (int t = 0; t < nk; ++t) {
    // stage(t) landed when only stage(t+1)'s 4 loads remain outstanding
    if (t + 1 < nk) asm volatile("s_waitcnt vmcnt(4)" ::: "memory");
    else            asm volatile("s_waitcnt vmcnt(0)" ::: "memory");
    __builtin_amdgcn_s_barrier();

    if (t + 2 < nk) {
      int nxt = cur + 2; if (nxt >= 3) nxt -= 3;
      GSTAGE(t + 2, nxt)
    }

    const char* Asl = (const char*)(sm + cur * 8192);
    const char* Bsl = Asl + 8192;
    {
      bf16x8 af[4], bfr[4];
#pragma unroll
      for (int m = 0; m < 4; ++m) {
        const int row = wr * 64 + m * 16 + r16;
        af[m] = *(const bf16x8*)(Asl + row * 64 + ((grp * 16) ^ ((row & 3) << 4)));
      }
#pragma unroll
      for (int n = 0; n < 4; ++n) {
        const int row = wc * 64 + n * 16 + r16;
        bfr[n] = *(const bf16x8*)(Bsl + row * 64 + ((grp * 16) ^ ((row & 3) << 4)));
      }
#pragma unroll
      for (int m = 0; m < 4; ++m)
#pragma unroll
        for (int n = 0; n < 4; ++n)
          acc[m][n] = __builtin_amdgcn_mfma_f32_16x16x32_bf16(af[m], bfr[n], acc[m][n], 0, 0, 0);
    }
    ++cur; if (cur == 3) cur = 0;
  }
#undef GSTAGE

  const float* bp = (MODE == 3) ? (seg == 0 ? bias0 : (seg == 1 ? bias1 : bias2)) : bias0;
  const float sc = (MODE == 3) ? (seg == 0 ? scale : 1.0f) : scale;

  if (MODE == 3 && seg == 2) {
    // ---- V^T epilogue: transpose each wave's 64x64 quadrant via LDS ----
    __syncthreads();  // all slots' ds_reads retired before reusing sm as T
    bf16* T = sm + w * (32 * 76);
    const int b = (m0 + wr * 64) >> 11;
    const int srow0 = (m0 + wr * 64) & 2047;
    bf16* base2 = (bf16*)Out + 2 * (size_t)NQKV;
#pragma unroll
    for (int p = 0; p < 2; ++p) {
#pragma unroll
      for (int nn = 0; nn < 2; ++nn) {
        const int n = 2 * p + nn;
#pragma unroll
        for (int mq = 0; mq < 4; ++mq)
#pragma unroll
          for (int r = 0; r < 4; ++r) {
            const int d_l = nn * 16 + r16;
            const int s_l = mq * 16 + grp * 4 + r;
            const int cs = (n0 + wc * 64 + n * 16 + r16) & 1023;
            T[d_l * 76 + s_l] = (bf16)(acc[mq][n][r] + bp[cs]);
          }
      }
      __syncthreads();
#pragma unroll
      for (int j = 0; j < 4; ++j) {
        const int d_l = j * 8 + (lane >> 3);
        const int scnk = lane & 7;
        const uint2 lo = *(const uint2*)&T[d_l * 76 + scnk * 8];
        const uint2 hi = *(const uint2*)&T[d_l * 76 + scnk * 8 + 4];
        const int cs = (n0 + wc * 64 + p * 32 + d_l) & 1023;
        const int hh = cs >> 6, dd = cs & 63;
        bf16* dst = base2 + ((size_t)(b * NH + hh) * HD + dd) * S_LEN + srow0 + scnk * 8;
        uint4 val; val.x = lo.x; val.y = lo.y; val.z = hi.x; val.w = hi.y;
        *(uint4*)dst = val;
      }
      __syncthreads();
    }
    return;
  }

#pragma unroll
  for (int m = 0; m < 4; ++m) {
#pragma unroll
    for (int n = 0; n < 4; ++n) {
#pragma unroll
      for (int r = 0; r < 4; ++r) {
        const int row = m0 + wr * 64 + m * 16 + grp * 4 + r;
        const int col = n0 + wc * 64 + n * 16 + r16;
        const int cs = col & 1023;
        const float v = (acc[m][n][r] + bp[cs]) * sc;
        if (MODE == 3) {  // seg 0/1: head-major
          const int b = row >> 11, s = row & 2047, h = cs >> 6, d = cs & 63;
          bf16* base = (bf16*)Out + (size_t)seg * NQKV;
          base[((size_t)(b * NH + h) * S_LEN + s) * HD + d] = (bf16)v;
        } else {
          ((float*)Out)[(size_t)row * N + col] = v;
        }
      }
    }
  }
}

// ---------------- causal flash attention: single-chunk blocks, 3/CU ------------
// (round-13 structure, session best: 45.0us, Occ 25.4%)
__global__ __launch_bounds__(256, 3) void attn_fwd13(
    const bf16* __restrict__ Qh, const bf16* __restrict__ Kh,
    const bf16* __restrict__ Vt, bf16* __restrict__ AO) {
  __shared__ __align__(16) bf16 Kl[3][64 * 64];
  __shared__ __align__(16) bf16 Vl[3][64 * 64];

  const int tid = threadIdx.x;
  const int lane = tid & 63, w = tid >> 6;
  const int q31 = lane & 31, h = lane >> 5;
  const int qh = w >> 1, kh = w & 1;
  const int koff = kh << 5;

  const int bid = blockIdx.x;
  const int xcd = bid & 7;
  const int within = bid >> 3;
  const int bh = xcd * 4 + (within & 3);
  const int c = 31 - (within >> 2);

  const bf16* Qb = Qh + (size_t)bh * S_LEN * HD;
  const bf16* Kb = Kh + (size_t)bh * S_LEN * HD;
  const bf16* Vb = Vt + (size_t)bh * HD * S_LEN;

  int stK[2], stV[2], stL[2];
#pragma unroll
  for (int i = 0; i < 2; ++i) {
    const int lin = i * 256 + tid;
    const int row = lin >> 3;
    const int colb = (lin & 7) * 16;
    const int scol = colb ^ ((row & 7) << 4);
    stK[i] = row * HD + (scol >> 1);
    stV[i] = row * S_LEN + (scol >> 1);
    stL[i] = lin * 8;
  }
  const int swz = (q31 & 7) << 4;

#define STAGE(t, buf)                                                          \
  {                                                                            \
    const bf16* kb_ = Kb + (size_t)(t) * 64 * HD;                              \
    const bf16* vb_ = Vb + (t) * 64;                                           \
    _Pragma("unroll") for (int i = 0; i < 2; ++i) {                            \
      gload_lds16(kb_ + stK[i], &Kl[buf][stL[i]]);                             \
      gload_lds16(vb_ + stV[i], &Vl[buf][stL[i]]);                             \
    }                                                                          \
  }

  {
    const int q0 = c << 6;
    const int nt = c + 1;
    const int q0w = q0 + (qh << 5);
    const int qg = q0w + q31;
    const int nt_w = (w == 1) ? nt - 1 : nt;
    const bool maskw = (w == 0) || (w == 3);

    bf16x8 qf[4];
#pragma unroll
    for (int ks = 0; ks < 4; ++ks)
      qf[ks] = *(const bf16x8*)&Qb[(size_t)qg * HD + ks * 16 + 8 * h];

    f32x16 acc0 = {}, acc1 = {};
    float m = -1e30f, l = 0.f;

    STAGE(0, 0)
    if (nt > 1) STAGE(1, 1)

    int cur = 0;
    for (int kt = 0; kt < nt; ++kt) {
      if (kt + 1 < nt) asm volatile("s_waitcnt vmcnt(4)" ::: "memory");
      else             asm volatile("s_waitcnt vmcnt(0)" ::: "memory");
      __builtin_amdgcn_s_barrier();

      if (kt + 2 < nt) {
        int nxt = cur + 2; if (nxt >= 3) nxt -= 3;
        STAGE(kt + 2, nxt)
      }

      if (kt < nt_w) {
        const bf16* KlC = &Kl[cur][0];
        const bf16* VlC = &Vl[cur][0];

        bf16x8 kf[4];
#pragma unroll
        for (int ks = 0; ks < 4; ++ks) {
          const int cc = (32 * ks + 16 * h) ^ swz;
          kf[ks] = *(const bf16x8*)((const char*)KlC + (koff + q31) * 128 + cc);
        }

        f32x16 p0 = {};
        __builtin_amdgcn_s_setprio(1);
#pragma unroll
        for (int ks = 0; ks < 4; ++ks)
          p0 = __builtin_amdgcn_mfma_f32_32x32x16_bf16(kf[ks], qf[ks], p0, 0, 0, 0);
        __builtin_amdgcn_s_setprio(0);

        bf16x8 vf[4];
#pragma unroll
        for (int ks = 0; ks < 2; ++ks)
#pragma unroll
          for (int db = 0; db < 2; ++db) {
            const int cc = (64 * kh + 32 * ks + 16 * h) ^ swz;
            vf[ks * 2 + db] =
                *(const bf16x8*)((const char*)VlC + (db * 32 + q31) * 128 + cc);
          }

        if (maskw && kt == nt - 1) {
#pragma unroll
          for (int r = 0; r < 16; ++r) {
            const int key = (kt << 6) + koff + (r & 3) + 8 * (r >> 2) + 4 * h;
            if (key > qg) p0[r] = -1e30f;
          }
        }
        float t_[16];
#pragma unroll
        for (int r = 0; r < 16; ++r) t_[r] = p0[r];
#pragma unroll
        for (int s = 8; s >= 1; s >>= 1)
#pragma unroll
          for (int r = 0; r < s; ++r) t_[r] = fmaxf(t_[r], t_[r + s]);
        const float pmax = fmaxf(t_[0], __shfl_xor(t_[0], 32));
        if (!__all(pmax - m <= 8.0f)) {
          const float mn = fmaxf(m, pmax);
          const float al = exp2f(m - mn);
          m = mn;
          l *= al;
#pragma unroll
          for (int r = 0; r < 16; ++r) { acc0[r] *= al; acc1[r] *= al; }
        }
        float sv[16];
#pragma unroll
        for (int r = 0; r < 16; ++r) {
          p0[r] = exp2f(p0[r] - m);
          sv[r] = p0[r];
        }
#pragma unroll
        for (int s = 8; s >= 1; s >>= 1)
#pragma unroll
          for (int r = 0; r < s; ++r) sv[r] += sv[r + s];
        l += sv[0] + __shfl_xor(sv[0], 32);

        unsigned wv[8];
#pragma unroll
        for (int mm = 0; mm < 8; ++mm)
          wv[mm] = packbf(p0[2 * mm], p0[2 * mm + 1]);
        pl32swap(wv[0], wv[2]);
        pl32swap(wv[1], wv[3]);
        pl32swap(wv[4], wv[6]);
        pl32swap(wv[5], wv[7]);

        __builtin_amdgcn_s_setprio(1);
        {
          u32x4 pu0 = {wv[0], wv[1], wv[2], wv[3]};
          const bf16x8 pf0 = __builtin_bit_cast(bf16x8, pu0);
          acc0 = __builtin_amdgcn_mfma_f32_32x32x16_bf16(vf[0], pf0, acc0, 0, 0, 0);
          acc1 = __builtin_amdgcn_mfma_f32_32x32x16_bf16(vf[1], pf0, acc1, 0, 0, 0);
          u32x4 pu1 = {wv[4], wv[5], wv[6], wv[7]};
          const bf16x8 pf1 = __builtin_bit_cast(bf16x8, pu1);
          acc0 = __builtin_amdgcn_mfma_f32_32x32x16_bf16(vf[2], pf1, acc0, 0, 0, 0);
          acc1 = __builtin_amdgcn_mfma_f32_32x32x16_bf16(vf[3], pf1, acc1, 0, 0, 0);
        }
        __builtin_amdgcn_s_setprio(0);
      }

      ++cur; if (cur == 3) cur = 0;
    }

    // ---- split-K combine across key-half waves (scratch = Kl area) ----
    float* scr = (float*)&Kl[0][0];
    float* s = scr + (size_t)qh * (64 * 34) + lane * 34;
    __syncthreads();
    if (kh) {
#pragma unroll
      for (int r = 0; r < 16; ++r) { s[r] = acc0[r]; s[16 + r] = acc1[r]; }
      s[32] = m;
      s[33] = l;
    }
    __syncthreads();
    if (!kh) {
      const float m1 = s[32], l1 = s[33];
      const float mn = fmaxf(m, m1);
      const float a0 = exp2f(m - mn), a1 = exp2f(m1 - mn);
      const float linv = 1.0f / (a0 * l + a1 * l1);
      const int b = bh >> 4, hh = bh & 15;
      bf16* orow = AO + ((size_t)(b * S_LEN + qg)) * DM + hh * HD;
#pragma unroll
      for (int mm = 0; mm < 4; ++mm) {
        bf16x4 ov0, ov1;
#pragma unroll
        for (int t2 = 0; t2 < 4; ++t2) {
          ov0[t2] = (bf16)((a0 * acc0[4 * mm + t2] + a1 * s[4 * mm + t2]) * linv);
          ov1[t2] = (bf16)((a0 * acc1[4 * mm + t2] + a1 * s[16 + 4 * mm + t2]) * linv);
        }
        *(bf16x4*)&orow[8 * mm + 4 * h] = ov0;
        *(bf16x4*)&orow[32 + 8 * mm + 4 * h] = ov1;
      }
    }
  }
#undef STAGE
}

// ---------------- launch ----------------
extern "C" void kernel_launch(void* const* d_in, const int* in_sizes, int n_in,
                              void* d_out, int out_size, void* d_ws, size_t ws_size,
                              hipStream_t stream) {
  const float* q  = (const float*)d_in[0];
  const float* k  = (const float*)d_in[1];
  const float* v  = (const float*)d_in[2];
  const float* Wq = (const float*)d_in[3];
  const float* bq = (const float*)d_in[4];
  const float* Wk = (const float*)d_in[5];
  const float* bk = (const float*)d_in[6];
  const float* Wv = (const float*)d_in[7];
  const float* bv = (const float*)d_in[8];
  const float* Wo = (const float*)d_in[9];
  const float* bo = (const float*)d_in[10];

  const int NTOK = 2 * S_LEN;          // 4096

  bf16* qb  = (bf16*)d_ws;             // q,k,v bf16: 3 * NQKV (consecutive)
  bf16* Wqb = qb + 3 * (size_t)NQKV;   // Wq,Wk,Wv,Wo bf16: 4 * NW (consecutive)
  bf16* Wob = Wqb + 3 * (size_t)NW;
  bf16* Qh  = Wqb + 4 * (size_t)NW;    // Qh,Kh,Vt bf16: 3 * NQKV (consecutive)
  bf16* Kh  = Qh + (size_t)NQKV;
  bf16* Vt  = Kh + (size_t)NQKV;
  bf16* AO  = Vt + (size_t)NQKV;

  const int cvt_blocks = (3 * NQKV + 4 * NW) / 8 / 256;
  cvt_all<<<cvt_blocks, 256, 0, stream>>>(q, k, v, Wq, Wk, Wv, Wo, qb);

  // fused QKV projection: M=4096, N=3072, K=1024
  gemm_bt<3><<<dim3(3 * DM / 128, NTOK / 128), 256, 0, stream>>>(
      qb, Wqb, bq, bk, bv, Qh, NTOK, 3 * DM, DM, QK_SCALE);

  // attention: 1024 single-chunk blocks x 256 threads, heavy-first, 3/CU
  attn_fwd13<<<dim3(1024), 256, 0, stream>>>(Qh, Kh, Vt, AO);

  // output projection -> fp32 d_out
  gemm_bt<2><<<dim3(DM / 128, NTOK / 128), 256, 0, stream>>>(
      AO, Wob, bo, bo, bo, d_out, NTOK, DM, DM, 1.0f);
}

// Round 22
// 109.240 us; speedup vs baseline: 1.6997x; 1.0078x over previous
//
#include <hip/hip_runtime.h>
#include <hip/hip_bf16.h>
#include <cstdint>
#include <cstddef>

typedef __bf16 bf16;
typedef __bf16 bf16x2 __attribute__((ext_vector_type(2)));
typedef __bf16 bf16x4 __attribute__((ext_vector_type(4)));
typedef __bf16 bf16x8 __attribute__((ext_vector_type(8)));
typedef float f32x4 __attribute__((ext_vector_type(4)));
typedef float f32x16 __attribute__((ext_vector_type(16)));
typedef unsigned int u32x4 __attribute__((ext_vector_type(4)));

#define S_LEN 2048
#define DM 1024
#define NH 16
#define HD 64
#define NQKV (4096 * 1024)   // tokens * DM
#define NW (1024 * 1024)
// (1/sqrt(64)) * log2(e): fold softmax scale + exp2 conversion into Q
#define QK_SCALE 0.18033688011112042f

__device__ __forceinline__ void gload_lds16(const bf16* g, bf16* l) {
  __builtin_amdgcn_global_load_lds(
      (const __attribute__((address_space(1))) void*)g,
      (__attribute__((address_space(3))) void*)l, 16, 0, 0);
}

__device__ __forceinline__ unsigned packbf(float lo, float hi) {
  bf16x2 t;
  t[0] = (bf16)lo;
  t[1] = (bf16)hi;
  return __builtin_bit_cast(unsigned, t);
}

// v_permlane32_swap_b32: new_a[l>=32] = b_old[l-32]; new_b[l<32] = a_old[l+32]
__device__ __forceinline__ void pl32swap(unsigned& a, unsigned& b) {
#if __has_builtin(__builtin_amdgcn_permlane32_swap)
  auto r = __builtin_amdgcn_permlane32_swap((int)a, (int)b, false, false);
  a = (unsigned)r[0];
  b = (unsigned)r[1];
#else
  asm volatile("v_permlane32_swap_b32 %0, %1" : "+v"(a), "+v"(b));
#endif
}

// ---------------- fused fp32 -> bf16 convert for all 7 tensors ----------------
__global__ __launch_bounds__(256) void cvt_all(
    const float* __restrict__ q, const float* __restrict__ k, const float* __restrict__ v,
    const float* __restrict__ Wq, const float* __restrict__ Wk, const float* __restrict__ Wv,
    const float* __restrict__ Wo, bf16* __restrict__ out) {
  const size_t i = ((size_t)blockIdx.x * 256 + threadIdx.x) * 8;
  const float* src;
  size_t off;
  if (i < (size_t)NQKV) { src = q; off = i; }
  else if (i < 2ull * NQKV) { src = k; off = i - NQKV; }
  else if (i < 3ull * NQKV) { src = v; off = i - 2ull * NQKV; }
  else {
    const size_t j = i - 3ull * NQKV;
    if (j < (size_t)NW) { src = Wq; off = j; }
    else if (j < 2ull * NW) { src = Wk; off = j - NW; }
    else if (j < 3ull * NW) { src = Wv; off = j - 2ull * NW; }
    else { src = Wo; off = j - 3ull * NW; }
  }
  const float4 a = *(const float4*)(src + off);
  const float4 b = *(const float4*)(src + off + 4);
  bf16x8 o;
  o[0] = (bf16)a.x; o[1] = (bf16)a.y; o[2] = (bf16)a.z; o[3] = (bf16)a.w;
  o[4] = (bf16)b.x; o[5] = (bf16)b.y; o[6] = (bf16)b.z; o[7] = (bf16)b.w;
  *(bf16x8*)(out + i) = o;
}

// ------------- output-projection GEMM (r21 proven, 128x128, MODE2 only) --------
__global__ __launch_bounds__(256, 3) void gemm_out(
    const bf16* __restrict__ A, const bf16* __restrict__ W,
    const float* __restrict__ bias0, float* __restrict__ Out,
    int M, int N, int K) {
  __shared__ __align__(16) bf16 sm[3 * 2 * 128 * 32];
  const int tid = threadIdx.x;
  const int lane = tid & 63, w = tid >> 6;
  const int wr = w >> 1, wc = w & 1;
  const int r16 = lane & 15, grp = lane >> 4;

  int flat = blockIdx.y * gridDim.x + blockIdx.x;
  const int cpx = (gridDim.x * gridDim.y) >> 3;
  flat = (flat & 7) * cpx + (flat >> 3);
  const int m0 = (flat / gridDim.x) * 128;
  const int n0 = (flat % gridDim.x) * 128;

  f32x4 acc[4][4] = {};

  int stG[2], stL[2];
#pragma unroll
  for (int j = 0; j < 2; ++j) {
    const int lin = j * 256 + tid;
    const int row = lin >> 2;
    const int ch = (lin & 3) ^ (row & 3);
    stG[j] = row * K + ch * 8;
    stL[j] = lin * 8;
  }

#define GSTAGE(t, s)                                                           \
  {                                                                            \
    const int k0_ = (t) << 5;                                                  \
    bf16* as_ = sm + (s) * 8192;                                               \
    bf16* bs_ = as_ + 4096;                                                    \
    _Pragma("unroll") for (int j = 0; j < 2; ++j) {                            \
      gload_lds16(&A[(size_t)m0 * K + k0_ + stG[j]], &as_[stL[j]]);            \
      gload_lds16(&W[(size_t)n0 * K + k0_ + stG[j]], &bs_[stL[j]]);            \
    }                                                                          \
  }

  const int nk = K >> 5;
  GSTAGE(0, 0)
  GSTAGE(1, 1)

  int cur = 0;
  for (int t = 0; t < nk; ++t) {
    if (t + 1 < nk) asm volatile("s_waitcnt vmcnt(4)" ::: "memory");
    else            asm volatile("s_waitcnt vmcnt(0)" ::: "memory");
    __builtin_amdgcn_s_barrier();

    if (t + 2 < nk) {
      int nxt = cur + 2; if (nxt >= 3) nxt -= 3;
      GSTAGE(t + 2, nxt)
    }

    const char* Asl = (const char*)(sm + cur * 8192);
    const char* Bsl = Asl + 8192;
    {
      bf16x8 af[4], bfr[4];
#pragma unroll
      for (int m = 0; m < 4; ++m) {
        const int row = wr * 64 + m * 16 + r16;
        af[m] = *(const bf16x8*)(Asl + row * 64 + ((grp * 16) ^ ((row & 3) << 4)));
      }
#pragma unroll
      for (int n = 0; n < 4; ++n) {
        const int row = wc * 64 + n * 16 + r16;
        bfr[n] = *(const bf16x8*)(Bsl + row * 64 + ((grp * 16) ^ ((row & 3) << 4)));
      }
#pragma unroll
      for (int m = 0; m < 4; ++m)
#pragma unroll
        for (int n = 0; n < 4; ++n)
          acc[m][n] = __builtin_amdgcn_mfma_f32_16x16x32_bf16(af[m], bfr[n], acc[m][n], 0, 0, 0);
    }
    ++cur; if (cur == 3) cur = 0;
  }
#undef GSTAGE

#pragma unroll
  for (int m = 0; m < 4; ++m)
#pragma unroll
    for (int n = 0; n < 4; ++n)
#pragma unroll
      for (int r = 0; r < 4; ++r) {
        const int row = m0 + wr * 64 + m * 16 + grp * 4 + r;
        const int col = n0 + wc * 64 + n * 16 + r16;
        Out[(size_t)row * N + col] = acc[m][n][r] + bias0[col & 1023];
      }
}

// ------------- fused QKV GEMM: 256x128 tile, 4 waves, BK=32, 3-slot ring -------
// Wave (wr = w>>1, wc = w&1) owns a 128x64 quadrant: acc[8][4], 32 MFMA/iter --
// 2x the MFMA per sync vs 128x128 (amortizes the per-iter vmcnt+barrier+stage
// fixed cost that r21 showed is the critical path). Proven r20 ledger: counted
// vmcnt(6) (6 loads/thread/stage), raw barrier, stage(t+2) after barrier.
// LDS 3 x 24KB = 72KB -> 2 blocks/CU; grid 24x16 = 384 blocks all co-resident.
// Chunk swizzle (r21-validated): source chunk' = chunk ^ (row&3); read XORs same.
// seg = n0>>10: seg0 Q head-major*QK_SCALE, seg1 K head-major, seg2 V^T.
__global__ __launch_bounds__(256, 2) void gemm_qkv(
    const bf16* __restrict__ A, const bf16* __restrict__ W,
    const float* __restrict__ bias0, const float* __restrict__ bias1,
    const float* __restrict__ bias2, bf16* __restrict__ Out, int K) {
  __shared__ __align__(16) bf16 sm[3 * 12288];  // 3 slots x (A 16KB + B 8KB)
  const int tid = threadIdx.x;
  const int lane = tid & 63, w = tid >> 6;
  const int wr = w >> 1, wc = w & 1;
  const int r16 = lane & 15, grp = lane >> 4;

  // XCD swizzle; grid = (24, 16), 384 % 8 == 0
  int flat = blockIdx.y * gridDim.x + blockIdx.x;
  const int cpx = (gridDim.x * gridDim.y) >> 3;
  flat = (flat & 7) * cpx + (flat >> 3);
  const int m0 = (flat / gridDim.x) * 256;
  const int n0 = (flat % gridDim.x) * 128;

  const int seg = n0 >> 10;
  const bf16* Ab = A + (size_t)seg * NQKV;

  f32x4 acc[8][4] = {};

  // staging: A 256x32 = 1024 chunks -> 4/thread; B 128x32 = 512 -> 2/thread
  int stGA[4], stLA[4], stGB[2], stLB[2];
#pragma unroll
  for (int j = 0; j < 4; ++j) {
    const int lin = j * 256 + tid;
    const int row = lin >> 2;
    const int ch = (lin & 3) ^ (row & 3);
    stGA[j] = row * K + ch * 8;
    stLA[j] = lin * 8;
  }
#pragma unroll
  for (int j = 0; j < 2; ++j) {
    const int lin = j * 256 + tid;
    const int row = lin >> 2;
    const int ch = (lin & 3) ^ (row & 3);
    stGB[j] = row * K + ch * 8;
    stLB[j] = lin * 8;
  }

#define QSTAGE(t, s)                                                           \
  {                                                                            \
    const int k0_ = (t) << 5;                                                  \
    bf16* as_ = sm + (s) * 12288;                                              \
    bf16* bs_ = as_ + 8192;                                                    \
    _Pragma("unroll") for (int j = 0; j < 4; ++j)                              \
      gload_lds16(&Ab[(size_t)m0 * K + k0_ + stGA[j]], &as_[stLA[j]]);         \
    _Pragma("unroll") for (int j = 0; j < 2; ++j)                              \
      gload_lds16(&W[(size_t)n0 * K + k0_ + stGB[j]], &bs_[stLB[j]]);          \
  }

  const int nk = K >> 5;   // 32
  QSTAGE(0, 0)
  QSTAGE(1, 1)

  int cur = 0;
  for (int t = 0; t < nk; ++t) {
    // stage(t) landed when only stage(t+1)'s 6 loads remain outstanding
    if (t + 1 < nk) asm volatile("s_waitcnt vmcnt(6)" ::: "memory");
    else            asm volatile("s_waitcnt vmcnt(0)" ::: "memory");
    __builtin_amdgcn_s_barrier();

    if (t + 2 < nk) {
      int nxt = cur + 2; if (nxt >= 3) nxt -= 3;
      QSTAGE(t + 2, nxt)
    }

    const char* Asl = (const char*)(sm + cur * 12288);
    const char* Bsl = Asl + 16384;
    {
      bf16x8 af[8], bfr[4];
#pragma unroll
      for (int m = 0; m < 8; ++m) {
        const int row = wr * 128 + m * 16 + r16;
        af[m] = *(const bf16x8*)(Asl + row * 64 + ((grp * 16) ^ ((row & 3) << 4)));
      }
#pragma unroll
      for (int n = 0; n < 4; ++n) {
        const int row = wc * 64 + n * 16 + r16;
        bfr[n] = *(const bf16x8*)(Bsl + row * 64 + ((grp * 16) ^ ((row & 3) << 4)));
      }
      __builtin_amdgcn_s_setprio(1);
#pragma unroll
      for (int m = 0; m < 8; ++m)
#pragma unroll
        for (int n = 0; n < 4; ++n)
          acc[m][n] = __builtin_amdgcn_mfma_f32_16x16x32_bf16(af[m], bfr[n], acc[m][n], 0, 0, 0);
      __builtin_amdgcn_s_setprio(0);
    }
    ++cur; if (cur == 3) cur = 0;
  }
#undef QSTAGE

  const float* bp = (seg == 0 ? bias0 : (seg == 1 ? bias1 : bias2));
  const float sc = (seg == 0 ? QK_SCALE : 1.0f);

  if (seg == 2) {
    // ---- V^T epilogue: wave quadrant = 128 s-rows x 64 d-cols, one head ----
    // (n0 + wc*64 is 64-aligned -> hh fixed, dd = n*16+r16 in [0,64))
    __syncthreads();  // all slots' ds_reads retired before reusing sm as T
    bf16* T = sm + w * (32 * 132);   // per-wave [32 d][128 s], pitch 132
    const int srow_base = m0 + wr * 128;
    const int b = srow_base >> 11;
    const int srow0 = srow_base & 2047;
    const int hh = ((n0 + wc * 64) & 1023) >> 6;
    bf16* base2 = Out + 2 * (size_t)NQKV;
#pragma unroll
    for (int p = 0; p < 2; ++p) {
#pragma unroll
      for (int nn = 0; nn < 2; ++nn) {
        const int n = 2 * p + nn;
        const int cs = (n0 + wc * 64 + n * 16 + r16) & 1023;
        const float bb = bp[cs];
#pragma unroll
        for (int mq = 0; mq < 8; ++mq)
#pragma unroll
          for (int r = 0; r < 4; ++r) {
            const int d_l = nn * 16 + r16;
            const int s_l = mq * 16 + grp * 4 + r;
            T[d_l * 132 + s_l] = (bf16)(acc[mq][n][r] + bb);
          }
      }
      __syncthreads();
#pragma unroll
      for (int j = 0; j < 8; ++j) {
        const int d_l = j * 4 + (lane >> 4);   // 0..31
        const int scnk = lane & 15;            // 0..15 (16B chunks along s)
        const uint2 lo = *(const uint2*)&T[d_l * 132 + scnk * 8];
        const uint2 hi = *(const uint2*)&T[d_l * 132 + scnk * 8 + 4];
        const int dd = p * 32 + d_l;
        bf16* dst = base2 + ((size_t)(b * NH + hh) * HD + dd) * S_LEN + srow0 + scnk * 8;
        uint4 val; val.x = lo.x; val.y = lo.y; val.z = hi.x; val.w = hi.y;
        *(uint4*)dst = val;
      }
      __syncthreads();
    }
    return;
  }

  // seg 0/1: head-major [B,H,S,hd]
  bf16* base = Out + (size_t)seg * NQKV;
#pragma unroll
  for (int m = 0; m < 8; ++m)
#pragma unroll
    for (int n = 0; n < 4; ++n)
#pragma unroll
      for (int r = 0; r < 4; ++r) {
        const int row = m0 + wr * 128 + m * 16 + grp * 4 + r;
        const int col = n0 + wc * 64 + n * 16 + r16;
        const int cs = col & 1023;
        const float v = (acc[m][n][r] + bp[cs]) * sc;
        const int b = row >> 11, s = row & 2047, h = cs >> 6, d = cs & 63;
        base[((size_t)(b * NH + h) * S_LEN + s) * HD + d] = (bf16)v;
      }
}

// ---------------- causal flash attention: single-chunk blocks, 3/CU ------------
// (round-13 structure, session best: 45.0us, Occ 25.4%)
__global__ __launch_bounds__(256, 3) void attn_fwd13(
    const bf16* __restrict__ Qh, const bf16* __restrict__ Kh,
    const bf16* __restrict__ Vt, bf16* __restrict__ AO) {
  __shared__ __align__(16) bf16 Kl[3][64 * 64];
  __shared__ __align__(16) bf16 Vl[3][64 * 64];

  const int tid = threadIdx.x;
  const int lane = tid & 63, w = tid >> 6;
  const int q31 = lane & 31, h = lane >> 5;
  const int qh = w >> 1, kh = w & 1;
  const int koff = kh << 5;

  const int bid = blockIdx.x;
  const int xcd = bid & 7;
  const int within = bid >> 3;
  const int bh = xcd * 4 + (within & 3);
  const int c = 31 - (within >> 2);

  const bf16* Qb = Qh + (size_t)bh * S_LEN * HD;
  const bf16* Kb = Kh + (size_t)bh * S_LEN * HD;
  const bf16* Vb = Vt + (size_t)bh * HD * S_LEN;

  int stK[2], stV[2], stL[2];
#pragma unroll
  for (int i = 0; i < 2; ++i) {
    const int lin = i * 256 + tid;
    const int row = lin >> 3;
    const int colb = (lin & 7) * 16;
    const int scol = colb ^ ((row & 7) << 4);
    stK[i] = row * HD + (scol >> 1);
    stV[i] = row * S_LEN + (scol >> 1);
    stL[i] = lin * 8;
  }
  const int swz = (q31 & 7) << 4;

#define STAGE(t, buf)                                                          \
  {                                                                            \
    const bf16* kb_ = Kb + (size_t)(t) * 64 * HD;                              \
    const bf16* vb_ = Vb + (t) * 64;                                           \
    _Pragma("unroll") for (int i = 0; i < 2; ++i) {                            \
      gload_lds16(kb_ + stK[i], &Kl[buf][stL[i]]);                             \
      gload_lds16(vb_ + stV[i], &Vl[buf][stL[i]]);                             \
    }                                                                          \
  }

  {
    const int q0 = c << 6;
    const int nt = c + 1;
    const int q0w = q0 + (qh << 5);
    const int qg = q0w + q31;
    const int nt_w = (w == 1) ? nt - 1 : nt;
    const bool maskw = (w == 0) || (w == 3);

    bf16x8 qf[4];
#pragma unroll
    for (int ks = 0; ks < 4; ++ks)
      qf[ks] = *(const bf16x8*)&Qb[(size_t)qg * HD + ks * 16 + 8 * h];

    f32x16 acc0 = {}, acc1 = {};
    float m = -1e30f, l = 0.f;

    STAGE(0, 0)
    if (nt > 1) STAGE(1, 1)

    int cur = 0;
    for (int kt = 0; kt < nt; ++kt) {
      if (kt + 1 < nt) asm volatile("s_waitcnt vmcnt(4)" ::: "memory");
      else             asm volatile("s_waitcnt vmcnt(0)" ::: "memory");
      __builtin_amdgcn_s_barrier();

      if (kt + 2 < nt) {
        int nxt = cur + 2; if (nxt >= 3) nxt -= 3;
        STAGE(kt + 2, nxt)
      }

      if (kt < nt_w) {
        const bf16* KlC = &Kl[cur][0];
        const bf16* VlC = &Vl[cur][0];

        bf16x8 kf[4];
#pragma unroll
        for (int ks = 0; ks < 4; ++ks) {
          const int cc = (32 * ks + 16 * h) ^ swz;
          kf[ks] = *(const bf16x8*)((const char*)KlC + (koff + q31) * 128 + cc);
        }

        f32x16 p0 = {};
        __builtin_amdgcn_s_setprio(1);
#pragma unroll
        for (int ks = 0; ks < 4; ++ks)
          p0 = __builtin_amdgcn_mfma_f32_32x32x16_bf16(kf[ks], qf[ks], p0, 0, 0, 0);
        __builtin_amdgcn_s_setprio(0);

        bf16x8 vf[4];
#pragma unroll
        for (int ks = 0; ks < 2; ++ks)
#pragma unroll
          for (int db = 0; db < 2; ++db) {
            const int cc = (64 * kh + 32 * ks + 16 * h) ^ swz;
            vf[ks * 2 + db] =
                *(const bf16x8*)((const char*)VlC + (db * 32 + q31) * 128 + cc);
          }

        if (maskw && kt == nt - 1) {
#pragma unroll
          for (int r = 0; r < 16; ++r) {
            const int key = (kt << 6) + koff + (r & 3) + 8 * (r >> 2) + 4 * h;
            if (key > qg) p0[r] = -1e30f;
          }
        }
        float t_[16];
#pragma unroll
        for (int r = 0; r < 16; ++r) t_[r] = p0[r];
#pragma unroll
        for (int s = 8; s >= 1; s >>= 1)
#pragma unroll
          for (int r = 0; r < s; ++r) t_[r] = fmaxf(t_[r], t_[r + s]);
        const float pmax = fmaxf(t_[0], __shfl_xor(t_[0], 32));
        if (!__all(pmax - m <= 8.0f)) {
          const float mn = fmaxf(m, pmax);
          const float al = exp2f(m - mn);
          m = mn;
          l *= al;
#pragma unroll
          for (int r = 0; r < 16; ++r) { acc0[r] *= al; acc1[r] *= al; }
        }
        float sv[16];
#pragma unroll
        for (int r = 0; r < 16; ++r) {
          p0[r] = exp2f(p0[r] - m);
          sv[r] = p0[r];
        }
#pragma unroll
        for (int s = 8; s >= 1; s >>= 1)
#pragma unroll
          for (int r = 0; r < s; ++r) sv[r] += sv[r + s];
        l += sv[0] + __shfl_xor(sv[0], 32);

        unsigned wv[8];
#pragma unroll
        for (int mm = 0; mm < 8; ++mm)
          wv[mm] = packbf(p0[2 * mm], p0[2 * mm + 1]);
        pl32swap(wv[0], wv[2]);
        pl32swap(wv[1], wv[3]);
        pl32swap(wv[4], wv[6]);
        pl32swap(wv[5], wv[7]);

        __builtin_amdgcn_s_setprio(1);
        {
          u32x4 pu0 = {wv[0], wv[1], wv[2], wv[3]};
          const bf16x8 pf0 = __builtin_bit_cast(bf16x8, pu0);
          acc0 = __builtin_amdgcn_mfma_f32_32x32x16_bf16(vf[0], pf0, acc0, 0, 0, 0);
          acc1 = __builtin_amdgcn_mfma_f32_32x32x16_bf16(vf[1], pf0, acc1, 0, 0, 0);
          u32x4 pu1 = {wv[4], wv[5], wv[6], wv[7]};
          const bf16x8 pf1 = __builtin_bit_cast(bf16x8, pu1);
          acc0 = __builtin_amdgcn_mfma_f32_32x32x16_bf16(vf[2], pf1, acc0, 0, 0, 0);
          acc1 = __builtin_amdgcn_mfma_f32_32x32x16_bf16(vf[3], pf1, acc1, 0, 0, 0);
        }
        __builtin_amdgcn_s_setprio(0);
      }

      ++cur; if (cur == 3) cur = 0;
    }

    // ---- split-K combine across key-half waves (scratch = Kl area) ----
    float* scr = (float*)&Kl[0][0];
    float* s = scr + (size_t)qh * (64 * 34) + lane * 34;
    __syncthreads();
    if (kh) {
#pragma unroll
      for (int r = 0; r < 16; ++r) { s[r] = acc0[r]; s[16 + r] = acc1[r]; }
      s[32] = m;
      s[33] = l;
    }
    __syncthreads();
    if (!kh) {
      const float m1 = s[32], l1 = s[33];
      const float mn = fmaxf(m, m1);
      const float a0 = exp2f(m - mn), a1 = exp2f(m1 - mn);
      const float linv = 1.0f / (a0 * l + a1 * l1);
      const int b = bh >> 4, hh = bh & 15;
      bf16* orow = AO + ((size_t)(b * S_LEN + qg)) * DM + hh * HD;
#pragma unroll
      for (int mm = 0; mm < 4; ++mm) {
        bf16x4 ov0, ov1;
#pragma unroll
        for (int t2 = 0; t2 < 4; ++t2) {
          ov0[t2] = (bf16)((a0 * acc0[4 * mm + t2] + a1 * s[4 * mm + t2]) * linv);
          ov1[t2] = (bf16)((a0 * acc1[4 * mm + t2] + a1 * s[16 + 4 * mm + t2]) * linv);
        }
        *(bf16x4*)&orow[8 * mm + 4 * h] = ov0;
        *(bf16x4*)&orow[32 + 8 * mm + 4 * h] = ov1;
      }
    }
  }
#undef STAGE
}

// ---------------- launch ----------------
extern "C" void kernel_launch(void* const* d_in, const int* in_sizes, int n_in,
                              void* d_out, int out_size, void* d_ws, size_t ws_size,
                              hipStream_t stream) {
  const float* q  = (const float*)d_in[0];
  const float* k  = (const float*)d_in[1];
  const float* v  = (const float*)d_in[2];
  const float* Wq = (const float*)d_in[3];
  const float* bq = (const float*)d_in[4];
  const float* Wk = (const float*)d_in[5];
  const float* bk = (const float*)d_in[6];
  const float* Wv = (const float*)d_in[7];
  const float* bv = (const float*)d_in[8];
  const float* Wo = (const float*)d_in[9];
  const float* bo = (const float*)d_in[10];

  const int NTOK = 2 * S_LEN;          // 4096

  bf16* qb  = (bf16*)d_ws;             // q,k,v bf16: 3 * NQKV (consecutive)
  bf16* Wqb = qb + 3 * (size_t)NQKV;   // Wq,Wk,Wv,Wo bf16: 4 * NW (consecutive)
  bf16* Wob = Wqb + 3 * (size_t)NW;
  bf16* Qh  = Wqb + 4 * (size_t)NW;    // Qh,Kh,Vt bf16: 3 * NQKV (consecutive)
  bf16* Kh  = Qh + (size_t)NQKV;
  bf16* Vt  = Kh + (size_t)NQKV;
  bf16* AO  = Vt + (size_t)NQKV;

  const int cvt_blocks = (3 * NQKV + 4 * NW) / 8 / 256;
  cvt_all<<<cvt_blocks, 256, 0, stream>>>(q, k, v, Wq, Wk, Wv, Wo, qb);

  // fused QKV projection: M=4096, N=3072, K=1024; 256x128 tiles -> grid (24,16)
  gemm_qkv<<<dim3(3 * DM / 128, NTOK / 256), 256, 0, stream>>>(
      qb, Wqb, bq, bk, bv, Qh, DM);

  // attention: 1024 single-chunk blocks x 256 threads, heavy-first, 3/CU
  attn_fwd13<<<dim3(1024), 256, 0, stream>>>(Qh, Kh, Vt, AO);

  // output projection -> fp32 d_out (128x128 tiles, r21 proven)
  gemm_out<<<dim3(DM / 128, NTOK / 128), 256, 0, stream>>>(
      AO, Wob, bo, (float*)d_out, NTOK, DM, DM);
}